// Round 1
// baseline (4999.519 us; speedup 1.0000x reference)
//
#include <hip/hip_runtime.h>
#include <hip/hip_bf16.h>
#include <math.h>

#define H_    16
#define DN_   128
#define DR_   64
#define DV_   128
#define B_    2
#define L_    2048
#define HID_  2048
#define QL_   1536
#define KVL_  512

// ---------------------------------------------------------------- GEMM (fp32)
// C[M][N] = A[M][K] @ B[K][N], row-major with explicit leading dims.
// 64x64 tile, BK=16, 256 threads, 4x4 per thread.
__global__ __launch_bounds__(256) void gemm_f32(
    const float* __restrict__ A, int lda,
    const float* __restrict__ B, int ldb,
    float* __restrict__ C, int ldc,
    int M, int N, int K)
{
    __shared__ float As[16][68];   // [k][m], stride 68 -> 16B-aligned rows, ~2-way banks
    __shared__ float Bs[16][68];   // [k][n]
    const int tid = threadIdx.x;
    const int tx = tid & 15, ty = tid >> 4;
    const int m0 = blockIdx.y * 64, n0 = blockIdx.x * 64;

    float acc[4][4];
#pragma unroll
    for (int i = 0; i < 4; ++i)
#pragma unroll
        for (int j = 0; j < 4; ++j) acc[i][j] = 0.f;

    for (int k0 = 0; k0 < K; k0 += 16) {
#pragma unroll
        for (int i = 0; i < 4; ++i) {           // stage A tile: 64 m x 16 k
            int lin = i * 256 + tid;
            int m = lin >> 4, k = lin & 15;
            As[k][m] = A[(size_t)(m0 + m) * lda + k0 + k];
        }
#pragma unroll
        for (int i = 0; i < 4; ++i) {           // stage B tile: 16 k x 64 n
            int lin = i * 256 + tid;
            int k = lin >> 6, n = lin & 63;
            Bs[k][n] = B[(size_t)(k0 + k) * ldb + n0 + n];
        }
        __syncthreads();
#pragma unroll
        for (int k = 0; k < 16; ++k) {
            float4 a4 = *(const float4*)&As[k][ty * 4];
            float4 b4 = *(const float4*)&Bs[k][tx * 4];
            float av[4] = {a4.x, a4.y, a4.z, a4.w};
            float bv[4] = {b4.x, b4.y, b4.z, b4.w};
#pragma unroll
            for (int i = 0; i < 4; ++i)
#pragma unroll
                for (int j = 0; j < 4; ++j) acc[i][j] += av[i] * bv[j];
        }
        __syncthreads();
    }
#pragma unroll
    for (int i = 0; i < 4; ++i) {
        int m = m0 + ty * 4 + i;
        float4 o = make_float4(acc[i][0], acc[i][1], acc[i][2], acc[i][3]);
        *(float4*)&C[(size_t)m * ldc + n0 + tx * 4] = o;
    }
}

// ------------------------------------------------------------- RMSNorm (rows)
__global__ __launch_bounds__(256) void rmsnorm_rows(
    float* __restrict__ x, const float* __restrict__ w, int ncols, int rowstride)
{
    const int row = blockIdx.x;
    float* xr = x + (size_t)row * rowstride;
    const int tid = threadIdx.x;
    float ss = 0.f;
    for (int i = tid; i < ncols; i += 256) { float v = xr[i]; ss += v * v; }
#pragma unroll
    for (int o = 32; o > 0; o >>= 1) ss += __shfl_xor(ss, o);
    __shared__ float red[4];
    if ((tid & 63) == 0) red[tid >> 6] = ss;
    __syncthreads();
    float tot = red[0] + red[1] + red[2] + red[3];
    float sc = rsqrtf(tot / (float)ncols + 1e-6f);
    for (int i = tid; i < ncols; i += 256) xr[i] = xr[i] * sc * w[i];
}

// ----------------------------------------------------------------- YaRN RoPE
__device__ inline void yarn_cs(int l, int j, float& c, float& s)
{
    // inv_freq = 10000^(-2j/64)
    float invf = expf(-(float)(2 * j) * (9.210340371976184f / 64.f));
    float wavelen = 6.283185307179586f / invf;
    float ramp = (8192.f / wavelen - 1.f) * (1.f / 3.f);
    ramp = fminf(fmaxf(ramp, 0.f), 1.f);
    float invf2 = invf * (1.f - ramp) + invf * (1.f / 16.f) * ramp;
    float ang = (float)l * invf2;
    const float af = 1.2772588722239781f;   // 0.1*ln(16)+1
    c = cosf(ang) * af;
    s = sinf(ang) * af;
}

__global__ __launch_bounds__(256) void rope_q(float* __restrict__ q)
{
    int g = blockIdx.x * 256 + threadIdx.x;   // B*L*H*32 threads
    int j = g & 31;
    int h = (g >> 5) & 15;
    int bl = g >> 9;
    int l = bl & (L_ - 1);
    float c, s; yarn_cs(l, j, c, s);
    float* p = q + (size_t)bl * (H_ * (DN_ + DR_)) + h * (DN_ + DR_) + DN_;
    float x0 = p[j], x1 = p[j + 32];
    p[j]      = x0 * c - x1 * s;
    p[j + 32] = x1 * c + x0 * s;
}

__global__ __launch_bounds__(256) void rope_k(float* __restrict__ kvf)
{
    int g = blockIdx.x * 256 + threadIdx.x;   // B*L*32 threads
    int j = g & 31;
    int bl = g >> 5;
    int l = bl & (L_ - 1);
    float c, s; yarn_cs(l, j, c, s);
    float* p = kvf + (size_t)bl * (KVL_ + DR_) + KVL_;
    float x0 = p[j], x1 = p[j + 32];
    p[j]      = x0 * c - x1 * s;
    p[j + 32] = x1 * c + x0 * s;
}

// ------------------------------------------------------- Flash-style attention
// grid = (L/16, B*H), block = 256.  Each block: 16 q rows of one (b,h).
__global__ __launch_bounds__(256) void attn_f32(
    const float* __restrict__ q,    // [B*L][3072]
    const float* __restrict__ kv,   // [B*L][4096]  (per head: 128 nope | 128 v)
    const float* __restrict__ kvf,  // [B*L][576]   (cols 512..575 = roped k_rope)
    float* __restrict__ outp)       // [B*L][2048]
{
    const int bh = blockIdx.y;
    const int b = bh >> 4, h = bh & 15;
    const int qbase = blockIdx.x << 4;
    const int tid = threadIdx.x;
    const int r = tid >> 4, c = tid & 15;

    __shared__ float Qs[16][196];
    __shared__ float Ks[16][196];
    __shared__ float Vs[16][132];
    __shared__ float Ps[16][17];

    const float* qb = q + ((size_t)(b * L_) + qbase) * 3072 + h * 192;
    for (int i = tid; i < 16 * 192; i += 256) {
        int rr = i / 192, d = i - rr * 192;
        Qs[rr][d] = qb[(size_t)rr * 3072 + d];
    }

    float m = -INFINITY, ssum = 0.f;
    float acc[8];
#pragma unroll
    for (int j2 = 0; j2 < 8; ++j2) acc[j2] = 0.f;

    const int nkt = (qbase >> 4) + 1;
    const float scale = 0.07216878364870323f;   // 1/sqrt(192)

    for (int kt = 0; kt < nkt; ++kt) {
        const int kbase = kt << 4;
        __syncthreads();   // previous-iter LDS readers done (also orders Q staging)
        for (int i = tid; i < 16 * 192; i += 256) {
            int cc = i / 192, d = i - cc * 192;
            size_t row = (size_t)(b * L_ + kbase + cc);
            Ks[cc][d] = (d < 128) ? kv[row * 4096 + h * 256 + d]
                                  : kvf[row * 576 + 512 + (d - 128)];
        }
        for (int i = tid; i < 16 * 128; i += 256) {
            int cc = i >> 7, dv = i & 127;
            Vs[cc][dv] = kv[(size_t)(b * L_ + kbase + cc) * 4096 + h * 256 + 128 + dv];
        }
        __syncthreads();

        // ---- scores: thread (r,c) computes q_row(r) . k_row(c)
        float sc = 0.f;
#pragma unroll
        for (int d = 0; d < 192; d += 4) {
            float4 qv = *(const float4*)&Qs[r][d];
            float4 kk = *(const float4*)&Ks[c][d];
            sc += qv.x * kk.x + qv.y * kk.y + qv.z * kk.z + qv.w * kk.w;
        }
        sc *= scale;
        if (kbase + c > qbase + r) sc = -1e30f;

        float tmax = sc;
        tmax = fmaxf(tmax, __shfl_xor(tmax, 1));
        tmax = fmaxf(tmax, __shfl_xor(tmax, 2));
        tmax = fmaxf(tmax, __shfl_xor(tmax, 4));
        tmax = fmaxf(tmax, __shfl_xor(tmax, 8));
        float mNew = fmaxf(m, tmax);
        float p = expf(sc - mNew);
        float tsum = p;
        tsum += __shfl_xor(tsum, 1);
        tsum += __shfl_xor(tsum, 2);
        tsum += __shfl_xor(tsum, 4);
        tsum += __shfl_xor(tsum, 8);
        float alpha = expf(m - mNew);   // first tile: exp(-inf)=0
        ssum = ssum * alpha + tsum;
        m = mNew;
        Ps[r][c] = p;                   // wave-internal: no barrier needed

        // ---- PV: thread (r,c) owns dv = {4c..4c+3, 64+4c..64+4c+3}
#pragma unroll
        for (int j2 = 0; j2 < 8; ++j2) acc[j2] *= alpha;
#pragma unroll
        for (int cc = 0; cc < 16; ++cc) {
            float pv = Ps[r][cc];
            float4 v0 = *(const float4*)&Vs[cc][c * 4];
            float4 v1 = *(const float4*)&Vs[cc][c * 4 + 64];
            acc[0] += pv * v0.x; acc[1] += pv * v0.y;
            acc[2] += pv * v0.z; acc[3] += pv * v0.w;
            acc[4] += pv * v1.x; acc[5] += pv * v1.y;
            acc[6] += pv * v1.z; acc[7] += pv * v1.w;
        }
    }

    float inv = 1.f / ssum;
    float* orow = outp + ((size_t)(b * L_ + qbase + r)) * 2048 + h * 128;
    float4 o0 = make_float4(acc[0] * inv, acc[1] * inv, acc[2] * inv, acc[3] * inv);
    float4 o1 = make_float4(acc[4] * inv, acc[5] * inv, acc[6] * inv, acc[7] * inv);
    *(float4*)&orow[c * 4]      = o0;
    *(float4*)&orow[c * 4 + 64] = o1;
}

// ------------------------------------------------------------------- launcher
extern "C" void kernel_launch(void* const* d_in, const int* in_sizes, int n_in,
                              void* d_out, int out_size, void* d_ws, size_t ws_size,
                              hipStream_t stream)
{
    const float* x     = (const float*)d_in[0];
    const float* w_qa  = (const float*)d_in[1];
    const float* qnw   = (const float*)d_in[2];
    const float* w_qb  = (const float*)d_in[3];
    const float* w_kva = (const float*)d_in[4];
    const float* kvnw  = (const float*)d_in[5];
    const float* w_kvb = (const float*)d_in[6];
    const float* w_o   = (const float*)d_in[7];
    float* out = (float*)d_out;
    float* ws  = (float*)d_ws;

    const size_t BL = (size_t)B_ * L_;           // 4096
    float* q    = ws;                            // BL*3072
    float* kvb  = q + BL * 3072;                 // BL*4096
    float* kvf  = kvb + BL * 4096;               // BL*576
    float* qa   = kvf + BL * 576;                // BL*1536 (region reused by atto)
    float* atto = qa;                            // BL*2048 (qa dead by then)
    // total: BL*(3072+4096+576+2048) floats = 160.4 MB

    dim3 blk(256);

    // qa = x @ w_qa                       [4096,1536] = [4096,2048]@[2048,1536]
    gemm_f32<<<dim3(QL_ / 64, (int)(BL / 64)), blk, 0, stream>>>(
        x, HID_, w_qa, QL_, qa, QL_, (int)BL, QL_, HID_);
    // rmsnorm(qa) in place
    rmsnorm_rows<<<(int)BL, blk, 0, stream>>>(qa, qnw, QL_, QL_);
    // q = qa @ w_qb                       [4096,3072]
    gemm_f32<<<dim3(3072 / 64, (int)(BL / 64)), blk, 0, stream>>>(
        qa, QL_, w_qb, 3072, q, 3072, (int)BL, 3072, QL_);
    // kvf = x @ w_kva                     [4096,576]
    gemm_f32<<<dim3(576 / 64, (int)(BL / 64)), blk, 0, stream>>>(
        x, HID_, w_kva, 576, kvf, 576, (int)BL, 576, HID_);
    // rmsnorm(kvf[:, :512]) in place
    rmsnorm_rows<<<(int)BL, blk, 0, stream>>>(kvf, kvnw, KVL_, KVL_ + DR_);
    // kvb = kvf[:, :512] @ w_kvb          [4096,4096]
    gemm_f32<<<dim3(4096 / 64, (int)(BL / 64)), blk, 0, stream>>>(
        kvf, KVL_ + DR_, w_kvb, 4096, kvb, 4096, (int)BL, 4096, KVL_);
    // RoPE in place
    rope_q<<<(B_ * L_ * H_ * 32) / 256, blk, 0, stream>>>(q);
    rope_k<<<(B_ * L_ * 32) / 256, blk, 0, stream>>>(kvf);
    // attention
    attn_f32<<<dim3(L_ / 16, B_ * H_), blk, 0, stream>>>(q, kvb, kvf, atto);
    // out = atto @ w_o                    [4096,2048]
    gemm_f32<<<dim3(2048 / 64, (int)(BL / 64)), blk, 0, stream>>>(
        atto, 2048, w_o, 2048, out, 2048, (int)BL, 2048, 2048);
}

// Round 3
// 2449.443 us; speedup vs baseline: 2.0411x; 2.0411x over previous
//
#include <hip/hip_runtime.h>
#include <hip/hip_bf16.h>
#include <math.h>

#define H_    16
#define DN_   128
#define DR_   64
#define DV_   128
#define B_    2
#define L_    2048
#define HID_  2048
#define QL_   1536
#define KVL_  512

typedef __attribute__((ext_vector_type(8))) short bf16x8;
typedef __attribute__((ext_vector_type(4))) float f32x4;

// ---------------------------------------------------------------- GEMM (fp32)
__global__ __launch_bounds__(256) void gemm_f32(
    const float* __restrict__ A, int lda,
    const float* __restrict__ B, int ldb,
    float* __restrict__ C, int ldc,
    int M, int N, int K)
{
    __shared__ float As[16][68];
    __shared__ float Bs[16][68];
    const int tid = threadIdx.x;
    const int tx = tid & 15, ty = tid >> 4;
    const int m0 = blockIdx.y * 64, n0 = blockIdx.x * 64;

    float acc[4][4];
#pragma unroll
    for (int i = 0; i < 4; ++i)
#pragma unroll
        for (int j = 0; j < 4; ++j) acc[i][j] = 0.f;

    for (int k0 = 0; k0 < K; k0 += 16) {
#pragma unroll
        for (int i = 0; i < 4; ++i) {
            int lin = i * 256 + tid;
            int m = lin >> 4, k = lin & 15;
            As[k][m] = A[(size_t)(m0 + m) * lda + k0 + k];
        }
#pragma unroll
        for (int i = 0; i < 4; ++i) {
            int lin = i * 256 + tid;
            int k = lin >> 6, n = lin & 63;
            Bs[k][n] = B[(size_t)(k0 + k) * ldb + n0 + n];
        }
        __syncthreads();
#pragma unroll
        for (int k = 0; k < 16; ++k) {
            float4 a4 = *(const float4*)&As[k][ty * 4];
            float4 b4 = *(const float4*)&Bs[k][tx * 4];
            float av[4] = {a4.x, a4.y, a4.z, a4.w};
            float bv[4] = {b4.x, b4.y, b4.z, b4.w};
#pragma unroll
            for (int i = 0; i < 4; ++i)
#pragma unroll
                for (int j = 0; j < 4; ++j) acc[i][j] += av[i] * bv[j];
        }
        __syncthreads();
    }
#pragma unroll
    for (int i = 0; i < 4; ++i) {
        int m = m0 + ty * 4 + i;
        float4 o = make_float4(acc[i][0], acc[i][1], acc[i][2], acc[i][3]);
        *(float4*)&C[(size_t)m * ldc + n0 + tx * 4] = o;
    }
}

// ------------------------------------------------------------- RMSNorm (rows)
__global__ __launch_bounds__(256) void rmsnorm_rows(
    float* __restrict__ x, const float* __restrict__ w, int ncols, int rowstride)
{
    const int row = blockIdx.x;
    float* xr = x + (size_t)row * rowstride;
    const int tid = threadIdx.x;
    float ss = 0.f;
    for (int i = tid; i < ncols; i += 256) { float v = xr[i]; ss += v * v; }
#pragma unroll
    for (int o = 32; o > 0; o >>= 1) ss += __shfl_xor(ss, o);
    __shared__ float red[4];
    if ((tid & 63) == 0) red[tid >> 6] = ss;
    __syncthreads();
    float tot = red[0] + red[1] + red[2] + red[3];
    float sc = rsqrtf(tot / (float)ncols + 1e-6f);
    for (int i = tid; i < ncols; i += 256) xr[i] = xr[i] * sc * w[i];
}

// ----------------------------------------------------------------- YaRN RoPE
__device__ inline void yarn_cs(int l, int j, float& c, float& s)
{
    float invf = expf(-(float)(2 * j) * (9.210340371976184f / 64.f));
    float wavelen = 6.283185307179586f / invf;
    float ramp = (8192.f / wavelen - 1.f) * (1.f / 3.f);
    ramp = fminf(fmaxf(ramp, 0.f), 1.f);
    float invf2 = invf * (1.f - ramp) + invf * (1.f / 16.f) * ramp;
    float ang = (float)l * invf2;
    const float af = 1.2772588722239781f;
    c = cosf(ang) * af;
    s = sinf(ang) * af;
}

__global__ __launch_bounds__(256) void rope_k(float* __restrict__ kvf)
{
    int g = blockIdx.x * 256 + threadIdx.x;   // B*L*32 threads
    int j = g & 31;
    int bl = g >> 5;
    int l = bl & (L_ - 1);
    float c, s; yarn_cs(l, j, c, s);
    float* p = kvf + (size_t)bl * (KVL_ + DR_) + KVL_;
    float x0 = p[j], x1 = p[j + 32];
    p[j]      = x0 * c - x1 * s;
    p[j + 32] = x1 * c + x0 * s;
}

// --------------------------------------------- q fp32 -> Qb bf16 [bh][l][192]
__global__ __launch_bounds__(256) void qprep(
    const float* __restrict__ q, __hip_bfloat16* __restrict__ Qb)
{
    int idx = blockIdx.x * 256 + threadIdx.x;   // 32*2048*192 threads
    int d = idx % 192;
    int rest = idx / 192;
    int l = rest & (L_ - 1);
    int bh = rest >> 11;
    int b = bh >> 4, h = bh & 15;
    const float* row = q + (size_t)(b * L_ + l) * 3072 + h * 192;
    float val;
    if (d < 128) {
        val = row[d];
    } else if (d < 160) {
        int j = d - 128; float c, s; yarn_cs(l, j, c, s);
        val = row[128 + j] * c - row[160 + j] * s;
    } else {
        int j = d - 160; float c, s; yarn_cs(l, j, c, s);
        val = row[160 + j] * c + row[128 + j] * s;
    }
    Qb[idx] = __float2bfloat16(val);
}

// ------------------------------------- kvb V columns -> Vt bf16 [bh][128][2048]
__global__ __launch_bounds__(256) void vtrans(
    const float* __restrict__ kvb, __hip_bfloat16* __restrict__ Vt)
{
    __shared__ float t[64][33];
    const int tid = threadIdx.x;
    const int bh = blockIdx.z, b = bh >> 4, h = bh & 15;
    const int l0 = blockIdx.x * 64, dv0 = blockIdx.y * 32;

    {   // load 64 l x 32 dv
        int lr = tid >> 2, dc = (tid & 3) * 8;
        const float* src = kvb + (size_t)(b * L_ + l0 + lr) * 4096 + h * 256 + 128 + dv0 + dc;
#pragma unroll
        for (int j = 0; j < 8; ++j) t[lr][dc + j] = src[j];
    }
    __syncthreads();
    {   // write 32 dv x 64 l (transposed), 8 bf16 per thread
        int dvr = tid >> 3, lc = (tid & 7) * 8;
        union { uint4 v; __hip_bfloat16 h8[8]; } u;
#pragma unroll
        for (int j = 0; j < 8; ++j) u.h8[j] = __float2bfloat16(t[lc + j][dvr]);
        *(uint4*)&Vt[((size_t)bh * 128 + dv0 + dvr) * (size_t)L_ + l0 + lc] = u.v;
    }
}

// -------------------------------------------------------- MFMA flash attention
// grid (L/64, B*H), block 256 = 4 waves; wave w: q rows qb0+16w..+15. KVBLK=32.
#define LDK 200
#define LDV 56

__global__ __launch_bounds__(256) void attn_mfma(
    const __hip_bfloat16* __restrict__ Qb,  // [32][2048][192]
    const float* __restrict__ kvb,          // [4096][4096]
    const float* __restrict__ kvf,          // [4096][576], cols 512.. roped
    const __hip_bfloat16* __restrict__ Vt,  // [32][128][2048]
    float* __restrict__ outp)               // [4096][2048]
{
    __shared__ __hip_bfloat16 Kl[32][LDK];
    __shared__ __hip_bfloat16 Vl[128][LDV];
    __shared__ __hip_bfloat16 Pt[4][32][16];   // per-wave P^T [k][row]

    const int tid = threadIdx.x;
    const int w = tid >> 6, lane = tid & 63;
    const int g = lane >> 4, n = lane & 15;
    const int bh = blockIdx.y, b = bh >> 4, h = bh & 15;
    const int qb0 = blockIdx.x << 6;

    // Q fragments (A-operand, rows = n, k = g*8+j within each 32-chunk)
    bf16x8 qf[6];
    {
        const int qrow = qb0 + w * 16 + n;
        const __hip_bfloat16* qp = Qb + ((size_t)bh * L_ + qrow) * 192 + g * 8;
#pragma unroll
        for (int kk = 0; kk < 6; ++kk)
            qf[kk] = *(const bf16x8*)(qp + kk * 32);
    }

    f32x4 acc[8];
#pragma unroll
    for (int dt = 0; dt < 8; ++dt) acc[dt] = (f32x4){0.f, 0.f, 0.f, 0.f};
    float mi[4] = {-INFINITY, -INFINITY, -INFINITY, -INFINITY};
    float li[4] = {0.f, 0.f, 0.f, 0.f};

    const int ntiles = (qb0 >> 5) + 2;
    const int myqmax = qb0 + w * 16 + 15;
    const float scale = 0.07216878364870323f;   // 1/sqrt(192)

    for (int kt = 0; kt < ntiles; ++kt) {
        const int kb = kt << 5;
        __syncthreads();
        // stage K tile (32 rows x 192), fp32 -> bf16
        for (int i = tid; i < 32 * 192; i += 256) {
            int r = i / 192, d = i - r * 192;
            size_t row = (size_t)(b * L_ + kb + r);
            float v = (d < 128) ? kvb[row * 4096 + h * 256 + d]
                                : kvf[row * 576 + 512 + (d - 128)];
            Kl[r][d] = __float2bfloat16(v);
        }
        // stage V^T tile (128 dv x 32 k) from Vt: 16 bf16 (32 B) per thread
        {
            int dv = tid >> 1, half = tid & 1;
            const __hip_bfloat16* src = Vt + ((size_t)bh * 128 + dv) * (size_t)L_ + kb + half * 16;
            uint4 v0 = *(const uint4*)src;        // 8 bf16
            uint4 v1 = *(const uint4*)(src + 8);  // 8 bf16
            *(uint4*)&Vl[dv][half * 16]     = v0;
            *(uint4*)&Vl[dv][half * 16 + 8] = v1;
        }
        __syncthreads();

        if (kb > myqmax) continue;   // fully masked for this wave (barrier counts match)

        // ---- QK^T: two 16x16 col-tiles
        f32x4 s0 = (f32x4){0.f, 0.f, 0.f, 0.f};
        f32x4 s1 = (f32x4){0.f, 0.f, 0.f, 0.f};
#pragma unroll
        for (int kk = 0; kk < 6; ++kk) {
            bf16x8 k0 = *(const bf16x8*)&Kl[n][kk * 32 + g * 8];
            s0 = __builtin_amdgcn_mfma_f32_16x16x32_bf16(qf[kk], k0, s0, 0, 0, 0);
        }
#pragma unroll
        for (int kk = 0; kk < 6; ++kk) {
            bf16x8 k1 = *(const bf16x8*)&Kl[16 + n][kk * 32 + g * 8];
            s1 = __builtin_amdgcn_mfma_f32_16x16x32_bf16(qf[kk], k1, s1, 0, 0, 0);
        }

        // ---- mask + scale + online softmax (rows g*4+i, cols n / 16+n)
        float al[4];
#pragma unroll
        for (int i = 0; i < 4; ++i) {
            int qr = qb0 + w * 16 + g * 4 + i;
            float v0 = (kb + n      <= qr) ? s0[i] * scale : -1e30f;
            float v1 = (kb + 16 + n <= qr) ? s1[i] * scale : -1e30f;
            float mx = fmaxf(v0, v1);
            mx = fmaxf(mx, __shfl_xor(mx, 1));
            mx = fmaxf(mx, __shfl_xor(mx, 2));
            mx = fmaxf(mx, __shfl_xor(mx, 4));
            mx = fmaxf(mx, __shfl_xor(mx, 8));
            float mnew = fmaxf(mi[i], mx);
            float p0 = expf(v0 - mnew);
            float p1 = expf(v1 - mnew);
            float ts = p0 + p1;
            ts += __shfl_xor(ts, 1);
            ts += __shfl_xor(ts, 2);
            ts += __shfl_xor(ts, 4);
            ts += __shfl_xor(ts, 8);
            float a = expf(mi[i] - mnew);
            li[i] = li[i] * a + ts;
            mi[i] = mnew;
            al[i] = a;
            s0[i] = p0; s1[i] = p1;
        }
        {   // pack both col-tiles: Pt[w][n][g*4..+3] and Pt[w][16+n][g*4..+3]
            union { double d; __hip_bfloat16 hh[4]; } u0, u1;
#pragma unroll
            for (int i = 0; i < 4; ++i) {
                u0.hh[i] = __float2bfloat16(s0[i]);
                u1.hh[i] = __float2bfloat16(s1[i]);
            }
            *(double*)&Pt[w][n][g * 4]      = u0.d;
            *(double*)&Pt[w][16 + n][g * 4] = u1.d;
        }
        // drain the P^T LDS writes before cross-lane transposed reads (wave-internal)
        asm volatile("s_waitcnt lgkmcnt(0)" ::: "memory");
        __builtin_amdgcn_sched_barrier(0);

        // ---- P A-fragment: P[row=n][k=g*8+j] = Pt[k][n]
        union { bf16x8 v; short e[8]; } pf;
#pragma unroll
        for (int j = 0; j < 8; ++j)
            pf.e[j] = *(const short*)&Pt[w][g * 8 + j][n];

        // ---- PV: 8 dv col-tiles
#pragma unroll
        for (int dt = 0; dt < 8; ++dt) {
#pragma unroll
            for (int i = 0; i < 4; ++i) acc[dt][i] *= al[i];
            bf16x8 vf = *(const bf16x8*)&Vl[dt * 16 + n][g * 8];
            acc[dt] = __builtin_amdgcn_mfma_f32_16x16x32_bf16(pf.v, vf, acc[dt], 0, 0, 0);
        }
    }

    // epilogue
#pragma unroll
    for (int dt = 0; dt < 8; ++dt) {
#pragma unroll
        for (int i = 0; i < 4; ++i) {
            int qr = qb0 + w * 16 + g * 4 + i;
            outp[(size_t)(b * L_ + qr) * 2048 + h * 128 + dt * 16 + n] = acc[dt][i] / li[i];
        }
    }
}

// ------------------------------------------------------------------- launcher
extern "C" void kernel_launch(void* const* d_in, const int* in_sizes, int n_in,
                              void* d_out, int out_size, void* d_ws, size_t ws_size,
                              hipStream_t stream)
{
    const float* x     = (const float*)d_in[0];
    const float* w_qa  = (const float*)d_in[1];
    const float* qnw   = (const float*)d_in[2];
    const float* w_qb  = (const float*)d_in[3];
    const float* w_kva = (const float*)d_in[4];
    const float* kvnw  = (const float*)d_in[5];
    const float* w_kvb = (const float*)d_in[6];
    const float* w_o   = (const float*)d_in[7];
    float* out = (float*)d_out;
    float* ws  = (float*)d_ws;

    const size_t BL = (size_t)B_ * L_;   // 4096
    // region A: q fp32 (12.58M f) -> later atto (8.39M f) + Vt bf16 (tail)
    float* q    = ws;
    float* atto = ws;
    __hip_bfloat16* Vt = (__hip_bfloat16*)(ws + BL * 2048);
    // region B: kvb fp32
    float* kvb = ws + BL * 3072;
    // region C: kvf fp32
    float* kvf = kvb + BL * 4096;
    // region D: qa fp32 (dead after q gemm) -> Qb bf16
    float* qa = kvf + BL * 576;
    __hip_bfloat16* Qb = (__hip_bfloat16*)qa;
    // total: BL*(3072+4096+576+1536) floats = 152.0 MB

    dim3 blk(256);

    gemm_f32<<<dim3(QL_ / 64, (int)(BL / 64)), blk, 0, stream>>>(
        x, HID_, w_qa, QL_, qa, QL_, (int)BL, QL_, HID_);
    rmsnorm_rows<<<(int)BL, blk, 0, stream>>>(qa, qnw, QL_, QL_);
    gemm_f32<<<dim3(3072 / 64, (int)(BL / 64)), blk, 0, stream>>>(
        qa, QL_, w_qb, 3072, q, 3072, (int)BL, 3072, QL_);
    gemm_f32<<<dim3(576 / 64, (int)(BL / 64)), blk, 0, stream>>>(
        x, HID_, w_kva, 576, kvf, 576, (int)BL, 576, HID_);
    rmsnorm_rows<<<(int)BL, blk, 0, stream>>>(kvf, kvnw, KVL_, KVL_ + DR_);
    gemm_f32<<<dim3(4096 / 64, (int)(BL / 64)), blk, 0, stream>>>(
        kvf, KVL_ + DR_, w_kvb, 4096, kvb, 4096, (int)BL, 4096, KVL_);
    rope_k<<<(B_ * L_ * 32) / 256, blk, 0, stream>>>(kvf);
    // q fp32 -> Qb bf16 (with RoPE); q region then dead
    qprep<<<(32 * 2048 * 192) / 256, blk, 0, stream>>>(q, Qb);
    // kvb V cols -> Vt bf16 transposed (into tail of region A)
    vtrans<<<dim3(L_ / 64, 128 / 32, B_ * H_), blk, 0, stream>>>(kvb, Vt);
    // attention -> atto (head of region A)
    attn_mfma<<<dim3(L_ / 64, B_ * H_), blk, 0, stream>>>(Qb, kvb, kvf, Vt, atto);
    gemm_f32<<<dim3(2048 / 64, (int)(BL / 64)), blk, 0, stream>>>(
        atto, 2048, w_o, 2048, out, 2048, (int)BL, 2048, 2048);
}

// Round 4
// 755.743 us; speedup vs baseline: 6.6154x; 3.2411x over previous
//
#include <hip/hip_runtime.h>
#include <hip/hip_bf16.h>
#include <math.h>

#define H_    16
#define B_    2
#define L_    2048
#define HID_  2048
#define QL_   1536
#define KVL_  512

typedef unsigned short u16;
typedef __attribute__((ext_vector_type(8))) short bf16x8;
typedef __attribute__((ext_vector_type(4))) float f32x4;

__device__ __forceinline__ float bf2f(u16 u) {
    unsigned int x = ((unsigned int)u) << 16;
    return __uint_as_float(x);
}
__device__ __forceinline__ u16 f2bf(float f) {
    __hip_bfloat16 b = __float2bfloat16(f);
    return *(u16*)&b;
}
__device__ __forceinline__ void g2l16(const void* g, void* l) {
    __builtin_amdgcn_global_load_lds(
        (const __attribute__((address_space(1))) unsigned int*)g,
        (__attribute__((address_space(3))) unsigned int*)l,
        16, 0, 0);
}

// ----------------------------------------------------------------- YaRN table
__device__ inline void yarn_cs(int l, int j, float& c, float& s)
{
    float invf = expf(-(float)(2 * j) * (9.210340371976184f / 64.f));
    float wavelen = 6.283185307179586f / invf;
    float ramp = (8192.f / wavelen - 1.f) * (1.f / 3.f);
    ramp = fminf(fmaxf(ramp, 0.f), 1.f);
    float invf2 = invf * (1.f - ramp) + invf * (1.f / 16.f) * ramp;
    float ang = (float)l * invf2;
    const float af = 1.2772588722239781f;
    c = cosf(ang) * af;
    s = sinf(ang) * af;
}

__global__ __launch_bounds__(256) void yarn_tab(float* __restrict__ tab)
{
    int idx = blockIdx.x * 256 + threadIdx.x;   // 2048*32
    int l = idx >> 5, j = idx & 31;
    float c, s; yarn_cs(l, j, c, s);
    tab[l * 64 + j] = c;
    tab[l * 64 + 32 + j] = s;
}

// ------------------------------------------------------------ fp32 -> bf16 cvt
__global__ __launch_bounds__(256) void cvt_bf16(
    const float* __restrict__ in, u16* __restrict__ outp)
{
    int idx = blockIdx.x * 256 + threadIdx.x;   // one 8-elem chunk each
    float4 a = ((const float4*)in)[idx * 2];
    float4 b = ((const float4*)in)[idx * 2 + 1];
    union { uint4 v; u16 s[8]; } u;
    u.s[0] = f2bf(a.x); u.s[1] = f2bf(a.y); u.s[2] = f2bf(a.z); u.s[3] = f2bf(a.w);
    u.s[4] = f2bf(b.x); u.s[5] = f2bf(b.y); u.s[6] = f2bf(b.z); u.s[7] = f2bf(b.w);
    ((uint4*)outp)[idx] = u.v;
}

// ------------------------------------- weight transpose W[K][N] -> Wt[N][K] bf16
__global__ __launch_bounds__(256) void wtrans(
    const float* __restrict__ W, u16* __restrict__ Wt, int K, int N)
{
    __shared__ float t[64][65];
    const int n0 = blockIdx.x * 64, k0 = blockIdx.y * 64;
    const int tid = threadIdx.x;
    {
        int lr = tid >> 2, nc = (tid & 3) * 16;
        const float* src = W + (size_t)(k0 + lr) * N + n0 + nc;
#pragma unroll
        for (int j = 0; j < 16; j += 4) {
            float4 v = *(const float4*)(src + j);
            t[lr][nc + j] = v.x; t[lr][nc + j + 1] = v.y;
            t[lr][nc + j + 2] = v.z; t[lr][nc + j + 3] = v.w;
        }
    }
    __syncthreads();
    {
        int nr = tid >> 2, kc = (tid & 3) * 16;
        union { uint4 v[2]; u16 s[16]; } u;
#pragma unroll
        for (int j = 0; j < 16; ++j) u.s[j] = f2bf(t[kc + j][nr]);
        uint4* dst = (uint4*)(Wt + (size_t)(n0 + nr) * K + k0 + kc);
        dst[0] = u.v[0]; dst[1] = u.v[1];
    }
}

// ------------------------------------------------------- RMSNorm bf16 -> bf16
__global__ __launch_bounds__(256) void rmsnorm_b(
    const u16* __restrict__ in, int istride,
    u16* __restrict__ outp, int ostride,
    const float* __restrict__ w, int ncols)
{
    const int row = blockIdx.x, tid = threadIdx.x;
    const u16* ir = in + (size_t)row * istride;
    const int nch = ncols >> 3;
    float ss = 0.f;
    for (int c = tid; c < nch; c += 256) {
        union { uint4 v; u16 s[8]; } u;
        u.v = *(const uint4*)(ir + c * 8);
#pragma unroll
        for (int j = 0; j < 8; ++j) { float v = bf2f(u.s[j]); ss += v * v; }
    }
#pragma unroll
    for (int o = 32; o > 0; o >>= 1) ss += __shfl_xor(ss, o);
    __shared__ float red[4];
    if ((tid & 63) == 0) red[tid >> 6] = ss;
    __syncthreads();
    float tot = red[0] + red[1] + red[2] + red[3];
    float sc = rsqrtf(tot / (float)ncols + 1e-6f);
    u16* orow = outp + (size_t)row * ostride;
    for (int c = tid; c < nch; c += 256) {
        union { uint4 v; u16 s[8]; } u, o2;
        u.v = *(const uint4*)(ir + c * 8);
#pragma unroll
        for (int j = 0; j < 8; ++j)
            o2.s[j] = f2bf(bf2f(u.s[j]) * sc * w[c * 8 + j]);
        *(uint4*)(orow + c * 8) = o2.v;
    }
}

// ------------------------------------------------------------- GEMM epilogues
struct EpiStoreBf16_4 {          // BN=128
    u16* C; int ldc;
    __device__ void operator()(const f32x4* acc, int m0, int n0, int wr, int wc,
                               int g, int n) const {
#pragma unroll
        for (int mi = 0; mi < 4; ++mi)
#pragma unroll
            for (int ni = 0; ni < 4; ++ni)
#pragma unroll
                for (int i = 0; i < 4; ++i)
                    C[(size_t)(m0 + wr + mi * 16 + g * 4 + i) * ldc
                      + n0 + wc + ni * 16 + n] = f2bf(acc[mi * 4 + ni][i]);
    }
};
struct EpiStoreBf16_2 {          // BN=64
    u16* C; int ldc;
    __device__ void operator()(const f32x4* acc, int m0, int n0, int wr, int wc,
                               int g, int n) const {
#pragma unroll
        for (int mi = 0; mi < 4; ++mi)
#pragma unroll
            for (int ni = 0; ni < 2; ++ni)
#pragma unroll
                for (int i = 0; i < 4; ++i)
                    C[(size_t)(m0 + wr + mi * 16 + g * 4 + i) * ldc
                      + n0 + wc + ni * 16 + n] = f2bf(acc[mi * 2 + ni][i]);
    }
};
struct EpiStoreF32 {             // BN=128
    float* C; int ldc;
    __device__ void operator()(const f32x4* acc, int m0, int n0, int wr, int wc,
                               int g, int n) const {
#pragma unroll
        for (int mi = 0; mi < 4; ++mi)
#pragma unroll
            for (int ni = 0; ni < 4; ++ni)
#pragma unroll
                for (int i = 0; i < 4; ++i)
                    C[(size_t)(m0 + wr + mi * 16 + g * 4 + i) * ldc
                      + n0 + wc + ni * 16 + n] = acc[mi * 4 + ni][i];
    }
};
// q GEMM: write Qb[bh][l][192] with fused YaRN RoPE (BN=128, N=3072)
struct EpiQ {
    u16* Qb; const float* tab;
    __device__ void operator()(const f32x4* acc, int m0, int n0, int wr, int wc,
                               int g, int n) const {
        int c0 = n0 + wc;                 // multiple of 64
        int h = c0 / 192, r0 = c0 % 192;  // r0 in {0,64,128}
#pragma unroll
        for (int mi = 0; mi < 4; ++mi)
#pragma unroll
            for (int i = 0; i < 4; ++i) {
                int rr = m0 + wr + mi * 16 + g * 4 + i;
                int b = rr >> 11, l = rr & 2047;
                size_t base = ((size_t)(b * 16 + h) * 2048 + l) * 192;
                if (r0 < 128) {
#pragma unroll
                    for (int ni = 0; ni < 4; ++ni)
                        Qb[base + r0 + ni * 16 + n] = f2bf(acc[mi * 4 + ni][i]);
                } else {
#pragma unroll
                    for (int ni = 0; ni < 2; ++ni) {
                        int j = ni * 16 + n;
                        float cs = tab[l * 64 + j], sn = tab[l * 64 + 32 + j];
                        float lo = acc[mi * 4 + ni][i];
                        float hi = acc[mi * 4 + ni + 2][i];
                        Qb[base + 128 + j] = f2bf(lo * cs - hi * sn);
                        Qb[base + 160 + j] = f2bf(hi * cs + lo * sn);
                    }
                }
            }
    }
};
// kvb GEMM: split k_nope -> Kb[bh][l][192] (d<128), v -> Vc[bl][h*128+dv]
struct EpiKV {
    u16* Kb; u16* Vc;
    __device__ void operator()(const f32x4* acc, int m0, int n0, int wr, int wc,
                               int g, int n) const {
        int c0 = n0 + wc;                 // multiple of 64
        int h = c0 >> 8, r0 = c0 & 255;   // r0 in {0,64,128,192}
#pragma unroll
        for (int mi = 0; mi < 4; ++mi)
#pragma unroll
            for (int i = 0; i < 4; ++i) {
                int rr = m0 + wr + mi * 16 + g * 4 + i;
                int b = rr >> 11, l = rr & 2047;
                if (r0 < 128) {
                    size_t base = ((size_t)(b * 16 + h) * 2048 + l) * 192;
#pragma unroll
                    for (int ni = 0; ni < 4; ++ni)
                        Kb[base + r0 + ni * 16 + n] = f2bf(acc[mi * 4 + ni][i]);
                } else {
#pragma unroll
                    for (int ni = 0; ni < 4; ++ni)
                        Vc[(size_t)rr * 2048 + h * 128 + (r0 - 128) + ni * 16 + n]
                            = f2bf(acc[mi * 4 + ni][i]);
                }
            }
    }
};

// --------------------------------------------------------------- bf16 GEMM
// C[M][N] = A[M][K] @ Bt[N][K]^T. 128xBN tile, BK=32, 256 thr = 4 waves (2x2).
template<int BN, class Epi>
__global__ __launch_bounds__(256) void gemm_bf16(
    const u16* __restrict__ A, int lda,
    const u16* __restrict__ Bt, int ldb,
    int K, Epi epi)
{
    constexpr int NI = BN / 32;
    __shared__ u16 As[128 * 32];
    __shared__ u16 Bs[BN * 32];
    const int tid = threadIdx.x;
    const int w = tid >> 6, lane = tid & 63;
    const int g = lane >> 4, n = lane & 15;
    const int wr = (w >> 1) * 64, wc = (w & 1) * (BN / 2);
    const int m0 = blockIdx.y * 128, n0 = blockIdx.x * BN;
    const int arow = lane >> 2, acol = (lane & 3) * 8;

    f32x4 acc[4][NI];
#pragma unroll
    for (int mi = 0; mi < 4; ++mi)
#pragma unroll
        for (int ni = 0; ni < NI; ++ni) acc[mi][ni] = (f32x4){0.f, 0.f, 0.f, 0.f};

    for (int k0 = 0; k0 < K; k0 += 32) {
        __syncthreads();
#pragma unroll
        for (int i = 0; i < 2; ++i) {     // A tile: 128x32
            int seg = w * 2 + i;
            int row = seg * 16 + arow;
            g2l16(A + (size_t)(m0 + row) * lda + k0 + acol, &As[seg * 512]);
        }
        if constexpr (BN == 128) {
#pragma unroll
            for (int i = 0; i < 2; ++i) {
                int seg = w * 2 + i;
                int row = seg * 16 + arow;
                g2l16(Bt + (size_t)(n0 + row) * ldb + k0 + acol, &Bs[seg * 512]);
            }
        } else {
            int row = w * 16 + arow;
            g2l16(Bt + (size_t)(n0 + row) * ldb + k0 + acol, &Bs[w * 512]);
        }
        __syncthreads();

        bf16x8 af[4], bf[NI];
#pragma unroll
        for (int mi = 0; mi < 4; ++mi)
            af[mi] = *(const bf16x8*)&As[(wr + mi * 16 + n) * 32 + g * 8];
#pragma unroll
        for (int ni = 0; ni < NI; ++ni)
            bf[ni] = *(const bf16x8*)&Bs[(wc + ni * 16 + n) * 32 + g * 8];
#pragma unroll
        for (int mi = 0; mi < 4; ++mi)
#pragma unroll
            for (int ni = 0; ni < NI; ++ni)
                acc[mi][ni] = __builtin_amdgcn_mfma_f32_16x16x32_bf16(
                    af[mi], bf[ni], acc[mi][ni], 0, 0, 0);
    }
    epi(&acc[0][0], m0, n0, wr, wc, g, n);
}

// ------------------------------------------------ k_rope fill of Kb (d 128..191)
__global__ __launch_bounds__(256) void krope(
    const u16* __restrict__ kvf_b, u16* __restrict__ Kb,
    const float* __restrict__ tab)
{
    int idx = blockIdx.x * 256 + threadIdx.x;   // 32 bh * 2048 l * 32 j
    int j = idx & 31;
    int l = (idx >> 5) & 2047;
    int bh = idx >> 16;
    int b = bh >> 4;
    size_t row = (size_t)(b * 2048 + l);
    float x0 = bf2f(kvf_b[row * 576 + 512 + j]);
    float x1 = bf2f(kvf_b[row * 576 + 544 + j]);
    float cs = tab[l * 64 + j], sn = tab[l * 64 + 32 + j];
    size_t base = ((size_t)bh * 2048 + l) * 192;
    Kb[base + 128 + j] = f2bf(x0 * cs - x1 * sn);
    Kb[base + 160 + j] = f2bf(x1 * cs + x0 * sn);
}

// ----------------------------------- Vc[bl][h*128+dv] -> Vt[bh][128][2048] bf16
__global__ __launch_bounds__(256) void vtrans_b(
    const u16* __restrict__ Vc, u16* __restrict__ Vt)
{
    __shared__ u16 t[64][72];
    const int tid = threadIdx.x;
    const int bh = blockIdx.z, b = bh >> 4, h = bh & 15;
    const int l0 = blockIdx.x * 64, dv0 = blockIdx.y * 64;
    {
        int lr = tid >> 2, dc = (tid & 3) * 16;
        const u16* src = Vc + (size_t)(b * 2048 + l0 + lr) * 2048 + h * 128 + dv0 + dc;
        uint4 v0 = *(const uint4*)src;
        uint4 v1 = *(const uint4*)(src + 8);
        *(uint4*)&t[lr][dc] = v0;
        *(uint4*)&t[lr][dc + 8] = v1;
    }
    __syncthreads();
    {
        int dvr = tid >> 2, lc = (tid & 3) * 16;
        union { uint4 v[2]; u16 s[16]; } u;
#pragma unroll
        for (int j = 0; j < 16; ++j) u.s[j] = t[lc + j][dvr];
        uint4* dst = (uint4*)(Vt + ((size_t)bh * 128 + dv0 + dvr) * 2048 + l0 + lc);
        dst[0] = u.v[0]; dst[1] = u.v[1];
    }
}

// -------------------------------------------------------- MFMA flash attention
#define LDK 200
#define LDV 56

__global__ __launch_bounds__(256) void attn_mfma(
    const u16* __restrict__ Qb,   // [32][2048][192]
    const u16* __restrict__ Kb,   // [32][2048][192]
    const u16* __restrict__ Vt,   // [32][128][2048]
    u16* __restrict__ outp)       // [4096][2048] bf16
{
    __shared__ u16 Kl[32][LDK];
    __shared__ u16 Vl[128][LDV];
    __shared__ u16 Pt[4][32][16];

    const int tid = threadIdx.x;
    const int w = tid >> 6, lane = tid & 63;
    const int g = lane >> 4, n = lane & 15;
    const int bh = blockIdx.y, b = bh >> 4, h = bh & 15;
    const int qb0 = blockIdx.x << 6;

    bf16x8 qf[6];
    {
        const int qrow = qb0 + w * 16 + n;
        const u16* qp = Qb + ((size_t)bh * L_ + qrow) * 192 + g * 8;
#pragma unroll
        for (int kk = 0; kk < 6; ++kk)
            qf[kk] = *(const bf16x8*)(qp + kk * 32);
    }

    f32x4 acc[8];
#pragma unroll
    for (int dt = 0; dt < 8; ++dt) acc[dt] = (f32x4){0.f, 0.f, 0.f, 0.f};
    float mi[4] = {-INFINITY, -INFINITY, -INFINITY, -INFINITY};
    float li[4] = {0.f, 0.f, 0.f, 0.f};

    const int ntiles = (qb0 >> 5) + 2;
    const int myqmax = qb0 + w * 16 + 15;
    const float scale = 0.07216878364870323f;   // 1/sqrt(192)

    for (int kt = 0; kt < ntiles; ++kt) {
        const int kb = kt << 5;
        __syncthreads();
        {   // stage K tile 32x192 bf16 from Kb (uint2 = 4 elems each)
            const u16* Ksrc = Kb + ((size_t)bh * L_ + kb) * 192;
#pragma unroll
            for (int t = 0; t < 6; ++t) {
                int idx = t * 256 + tid;          // 0..1535
                int r = idx / 48, d = (idx % 48) * 4;
                *(uint2*)&Kl[r][d] = *(const uint2*)(Ksrc + (size_t)r * 192 + d);
            }
        }
        {   // stage V^T tile 128x32 bf16
            int dv = tid >> 1, half = tid & 1;
            const u16* src = Vt + ((size_t)bh * 128 + dv) * (size_t)L_ + kb + half * 16;
            uint4 v0 = *(const uint4*)src;
            uint4 v1 = *(const uint4*)(src + 8);
            *(uint4*)&Vl[dv][half * 16]     = v0;
            *(uint4*)&Vl[dv][half * 16 + 8] = v1;
        }
        __syncthreads();

        if (kb > myqmax) continue;

        f32x4 s0 = (f32x4){0.f, 0.f, 0.f, 0.f};
        f32x4 s1 = (f32x4){0.f, 0.f, 0.f, 0.f};
#pragma unroll
        for (int kk = 0; kk < 6; ++kk) {
            bf16x8 k0 = *(const bf16x8*)&Kl[n][kk * 32 + g * 8];
            s0 = __builtin_amdgcn_mfma_f32_16x16x32_bf16(qf[kk], k0, s0, 0, 0, 0);
        }
#pragma unroll
        for (int kk = 0; kk < 6; ++kk) {
            bf16x8 k1 = *(const bf16x8*)&Kl[16 + n][kk * 32 + g * 8];
            s1 = __builtin_amdgcn_mfma_f32_16x16x32_bf16(qf[kk], k1, s1, 0, 0, 0);
        }

        float al[4];
#pragma unroll
        for (int i = 0; i < 4; ++i) {
            int qr = qb0 + w * 16 + g * 4 + i;
            float v0 = (kb + n      <= qr) ? s0[i] * scale : -1e30f;
            float v1 = (kb + 16 + n <= qr) ? s1[i] * scale : -1e30f;
            float mx = fmaxf(v0, v1);
            mx = fmaxf(mx, __shfl_xor(mx, 1));
            mx = fmaxf(mx, __shfl_xor(mx, 2));
            mx = fmaxf(mx, __shfl_xor(mx, 4));
            mx = fmaxf(mx, __shfl_xor(mx, 8));
            float mnew = fmaxf(mi[i], mx);
            float p0 = expf(v0 - mnew);
            float p1 = expf(v1 - mnew);
            float ts = p0 + p1;
            ts += __shfl_xor(ts, 1);
            ts += __shfl_xor(ts, 2);
            ts += __shfl_xor(ts, 4);
            ts += __shfl_xor(ts, 8);
            float a = expf(mi[i] - mnew);
            li[i] = li[i] * a + ts;
            mi[i] = mnew;
            al[i] = a;
            s0[i] = p0; s1[i] = p1;
        }
        {
            union { double d; u16 hh[4]; } u0, u1;
#pragma unroll
            for (int i = 0; i < 4; ++i) {
                u0.hh[i] = f2bf(s0[i]);
                u1.hh[i] = f2bf(s1[i]);
            }
            *(double*)&Pt[w][n][g * 4]      = u0.d;
            *(double*)&Pt[w][16 + n][g * 4] = u1.d;
        }
        asm volatile("s_waitcnt lgkmcnt(0)" ::: "memory");
        __builtin_amdgcn_sched_barrier(0);

        union { bf16x8 v; short e[8]; } pf;
#pragma unroll
        for (int j = 0; j < 8; ++j)
            pf.e[j] = *(const short*)&Pt[w][g * 8 + j][n];

#pragma unroll
        for (int dt = 0; dt < 8; ++dt) {
#pragma unroll
            for (int i = 0; i < 4; ++i) acc[dt][i] *= al[i];
            bf16x8 vf = *(const bf16x8*)&Vl[dt * 16 + n][g * 8];
            acc[dt] = __builtin_amdgcn_mfma_f32_16x16x32_bf16(pf.v, vf, acc[dt], 0, 0, 0);
        }
    }

#pragma unroll
    for (int dt = 0; dt < 8; ++dt) {
#pragma unroll
        for (int i = 0; i < 4; ++i) {
            int qr = qb0 + w * 16 + g * 4 + i;
            outp[(size_t)(b * L_ + qr) * 2048 + h * 128 + dt * 16 + n]
                = f2bf(acc[dt][i] / li[i]);
        }
    }
}

// ------------------------------------------------------------------- launcher
extern "C" void kernel_launch(void* const* d_in, const int* in_sizes, int n_in,
                              void* d_out, int out_size, void* d_ws, size_t ws_size,
                              hipStream_t stream)
{
    const float* x     = (const float*)d_in[0];
    const float* w_qa  = (const float*)d_in[1];
    const float* qnw   = (const float*)d_in[2];
    const float* w_qb  = (const float*)d_in[3];
    const float* w_kva = (const float*)d_in[4];
    const float* kvnw  = (const float*)d_in[5];
    const float* w_kvb = (const float*)d_in[6];
    const float* w_o   = (const float*)d_in[7];
    float* out = (float*)d_out;
    u16* W = (u16*)d_ws;

    // ---- workspace layout (u16 elems), total 65,929,216 = 131.9 MB
    const size_t o_wt_qa  = 0;
    const size_t o_wt_qb  = o_wt_qa  + (size_t)2048 * 1536;
    const size_t o_wt_kva = o_wt_qb  + (size_t)1536 * 3072;
    const size_t o_wt_kvb = o_wt_kva + (size_t)2048 * 576;
    const size_t o_wt_o   = o_wt_kvb + (size_t)512 * 4096;
    const size_t o_tab    = o_wt_o   + (size_t)2048 * 2048;   // float[2048*64]
    const size_t o_Qb     = o_tab    + 262144;
    const size_t o_Kb     = o_Qb     + 12582912;  // also qaR_b(+0), qa_b(+6291456)
    const size_t o_Vt     = o_Kb     + 12582912;  // also kvf_b(+0), kvc_b(+2359296)
    const size_t o_Vc     = o_Vt     + 8388608;   // also atto_b
    const size_t o_xb     = o_Vc     + 8388608;

    u16* Wt_qa  = W + o_wt_qa;
    u16* Wt_qb  = W + o_wt_qb;
    u16* Wt_kva = W + o_wt_kva;
    u16* Wt_kvb = W + o_wt_kvb;
    u16* Wt_o   = W + o_wt_o;
    float* tab  = (float*)(W + o_tab);
    u16* Qb     = W + o_Qb;
    u16* qaR_b  = W + o_Kb;
    u16* qa_b   = W + o_Kb + 6291456;
    u16* Kb     = W + o_Kb;
    u16* kvf_b  = W + o_Vt;
    u16* kvc_b  = W + o_Vt + 2359296;
    u16* Vt     = W + o_Vt;
    u16* Vc     = W + o_Vc;
    u16* atto_b = W + o_Vc;
    u16* x_b    = W + o_xb;

    dim3 blk(256);

    yarn_tab<<<(2048 * 32) / 256, blk, 0, stream>>>(tab);
    cvt_bf16<<<4096, blk, 0, stream>>>(x, x_b);                 // 8.39M elems
    wtrans<<<dim3(1536 / 64, 2048 / 64), blk, 0, stream>>>(w_qa,  Wt_qa,  2048, 1536);
    wtrans<<<dim3(3072 / 64, 1536 / 64), blk, 0, stream>>>(w_qb,  Wt_qb,  1536, 3072);
    wtrans<<<dim3( 576 / 64, 2048 / 64), blk, 0, stream>>>(w_kva, Wt_kva, 2048, 576);
    wtrans<<<dim3(4096 / 64,  512 / 64), blk, 0, stream>>>(w_kvb, Wt_kvb, 512, 4096);
    wtrans<<<dim3(2048 / 64, 2048 / 64), blk, 0, stream>>>(w_o,   Wt_o,   2048, 2048);

    // q chain
    gemm_bf16<128, EpiStoreBf16_4><<<dim3(12, 32), blk, 0, stream>>>(
        x_b, 2048, Wt_qa, 2048, 2048, EpiStoreBf16_4{qaR_b, 1536});
    rmsnorm_b<<<4096, blk, 0, stream>>>(qaR_b, 1536, qa_b, 1536, qnw, 1536);
    gemm_bf16<128, EpiQ><<<dim3(24, 32), blk, 0, stream>>>(
        qa_b, 1536, Wt_qb, 1536, 1536, EpiQ{Qb, tab});

    // kv chain
    gemm_bf16<64, EpiStoreBf16_2><<<dim3(9, 32), blk, 0, stream>>>(
        x_b, 2048, Wt_kva, 2048, 2048, EpiStoreBf16_2{kvf_b, 576});
    rmsnorm_b<<<4096, blk, 0, stream>>>(kvf_b, 576, kvc_b, 512, kvnw, 512);
    gemm_bf16<128, EpiKV><<<dim3(32, 32), blk, 0, stream>>>(
        kvc_b, 512, Wt_kvb, 512, 512, EpiKV{Kb, Vc});
    krope<<<(32 * 2048 * 32) / 256, blk, 0, stream>>>(kvf_b, Kb, tab);
    vtrans_b<<<dim3(32, 1, 32), dim3(256), 0, stream>>>(Vc, Vt);        // dv0=0
    vtrans_b<<<dim3(32, 1, 32), dim3(256), 0, stream>>>(Vc + 64, Vt + (size_t)64 * 2048); // dv0=64 hack? no — see below

    // attention + output projection
    attn_mfma<<<dim3(32, 32), blk, 0, stream>>>(Qb, Kb, Vt, atto_b);
    gemm_bf16<128, EpiStoreF32><<<dim3(16, 32), blk, 0, stream>>>(
        atto_b, 2048, Wt_o, 2048, 2048, EpiStoreF32{out, 2048});
    // NOTE: the two vtrans_b launches above are equivalent to a single
    // launch with gridDim.y=2; pointer-offset form kept deliberately wrong-proof:
    // Vc+64 shifts dv0 by 64 within a row; Vt offset shifts the dv row block.
}

// Round 5
// 435.552 us; speedup vs baseline: 11.4786x; 1.7351x over previous
//
#include <hip/hip_runtime.h>
#include <hip/hip_bf16.h>
#include <math.h>

#define H_    16
#define B_    2
#define L_    2048
#define HID_  2048
#define QL_   1536
#define KVL_  512

typedef unsigned short u16;
typedef __attribute__((ext_vector_type(8))) short bf16x8;
typedef __attribute__((ext_vector_type(4))) float f32x4;

__device__ __forceinline__ float bf2f(u16 u) {
    unsigned int x = ((unsigned int)u) << 16;
    return __uint_as_float(x);
}
__device__ __forceinline__ u16 f2bf(float f) {
    __hip_bfloat16 b = __float2bfloat16(f);
    return *(u16*)&b;
}
__device__ __forceinline__ void g2l16(const void* g, void* l) {
    __builtin_amdgcn_global_load_lds(
        (const __attribute__((address_space(1))) unsigned int*)g,
        (__attribute__((address_space(3))) unsigned int*)l,
        16, 0, 0);
}
// Kb row swizzle: element (l, d) of a K row is stored at column kswz(l, d)
__device__ __forceinline__ int kswz(int l, int d) {
    return (((d >> 3) ^ (l & 7)) << 3) | (d & 7);
}

// ----------------------------------------------------------------- YaRN table
__device__ inline void yarn_cs(int l, int j, float& c, float& s)
{
    float invf = expf(-(float)(2 * j) * (9.210340371976184f / 64.f));
    float wavelen = 6.283185307179586f / invf;
    float ramp = (8192.f / wavelen - 1.f) * (1.f / 3.f);
    ramp = fminf(fmaxf(ramp, 0.f), 1.f);
    float invf2 = invf * (1.f - ramp) + invf * (1.f / 16.f) * ramp;
    float ang = (float)l * invf2;
    const float af = 1.2772588722239781f;
    c = cosf(ang) * af;
    s = sinf(ang) * af;
}

__global__ __launch_bounds__(256) void yarn_tab(float* __restrict__ tab)
{
    int idx = blockIdx.x * 256 + threadIdx.x;   // 2048*32
    int l = idx >> 5, j = idx & 31;
    float c, s; yarn_cs(l, j, c, s);
    tab[l * 64 + j] = c;
    tab[l * 64 + 32 + j] = s;
}

// ------------------------------------------------------------ fp32 -> bf16 cvt
__global__ __launch_bounds__(256) void cvt_bf16(
    const float* __restrict__ in, u16* __restrict__ outp)
{
    int idx = blockIdx.x * 256 + threadIdx.x;
    float4 a = ((const float4*)in)[idx * 2];
    float4 b = ((const float4*)in)[idx * 2 + 1];
    union { uint4 v; u16 s[8]; } u;
    u.s[0] = f2bf(a.x); u.s[1] = f2bf(a.y); u.s[2] = f2bf(a.z); u.s[3] = f2bf(a.w);
    u.s[4] = f2bf(b.x); u.s[5] = f2bf(b.y); u.s[6] = f2bf(b.z); u.s[7] = f2bf(b.w);
    ((uint4*)outp)[idx] = u.v;
}

// ------------------------------------- weight transpose W[K][N] -> Wt[N][K] bf16
__global__ __launch_bounds__(256) void wtrans(
    const float* __restrict__ W, u16* __restrict__ Wt, int K, int N)
{
    __shared__ float t[64][65];
    const int n0 = blockIdx.x * 64, k0 = blockIdx.y * 64;
    const int tid = threadIdx.x;
    {
        int lr = tid >> 2, nc = (tid & 3) * 16;
        const float* src = W + (size_t)(k0 + lr) * N + n0 + nc;
#pragma unroll
        for (int j = 0; j < 16; j += 4) {
            float4 v = *(const float4*)(src + j);
            t[lr][nc + j] = v.x; t[lr][nc + j + 1] = v.y;
            t[lr][nc + j + 2] = v.z; t[lr][nc + j + 3] = v.w;
        }
    }
    __syncthreads();
    {
        int nr = tid >> 2, kc = (tid & 3) * 16;
        union { uint4 v[2]; u16 s[16]; } u;
#pragma unroll
        for (int j = 0; j < 16; ++j) u.s[j] = f2bf(t[kc + j][nr]);
        uint4* dst = (uint4*)(Wt + (size_t)(n0 + nr) * K + k0 + kc);
        dst[0] = u.v[0]; dst[1] = u.v[1];
    }
}

// ------------------------------------------------------- RMSNorm bf16 -> bf16
__global__ __launch_bounds__(256) void rmsnorm_b(
    const u16* __restrict__ in, int istride,
    u16* __restrict__ outp, int ostride,
    const float* __restrict__ w, int ncols)
{
    const int row = blockIdx.x, tid = threadIdx.x;
    const u16* ir = in + (size_t)row * istride;
    const int nch = ncols >> 3;
    float ss = 0.f;
    for (int c = tid; c < nch; c += 256) {
        union { uint4 v; u16 s[8]; } u;
        u.v = *(const uint4*)(ir + c * 8);
#pragma unroll
        for (int j = 0; j < 8; ++j) { float v = bf2f(u.s[j]); ss += v * v; }
    }
#pragma unroll
    for (int o = 32; o > 0; o >>= 1) ss += __shfl_xor(ss, o);
    __shared__ float red[4];
    if ((tid & 63) == 0) red[tid >> 6] = ss;
    __syncthreads();
    float tot = red[0] + red[1] + red[2] + red[3];
    float sc = rsqrtf(tot / (float)ncols + 1e-6f);
    u16* orow = outp + (size_t)row * ostride;
    for (int c = tid; c < nch; c += 256) {
        union { uint4 v; u16 s[8]; } u, o2;
        u.v = *(const uint4*)(ir + c * 8);
#pragma unroll
        for (int j = 0; j < 8; ++j)
            o2.s[j] = f2bf(bf2f(u.s[j]) * sc * w[c * 8 + j]);
        *(uint4*)(orow + c * 8) = o2.v;
    }
}

// ------------------------------------------------------------- GEMM epilogues
struct EpiStoreBf16_4 {          // BN=128
    u16* C; int ldc;
    __device__ void operator()(const f32x4* acc, int m0, int n0, int wr, int wc,
                               int g, int n) const {
#pragma unroll
        for (int mi = 0; mi < 4; ++mi)
#pragma unroll
            for (int ni = 0; ni < 4; ++ni)
#pragma unroll
                for (int i = 0; i < 4; ++i)
                    C[(size_t)(m0 + wr + mi * 16 + g * 4 + i) * ldc
                      + n0 + wc + ni * 16 + n] = f2bf(acc[mi * 4 + ni][i]);
    }
};
struct EpiStoreBf16_2 {          // BN=64
    u16* C; int ldc;
    __device__ void operator()(const f32x4* acc, int m0, int n0, int wr, int wc,
                               int g, int n) const {
#pragma unroll
        for (int mi = 0; mi < 4; ++mi)
#pragma unroll
            for (int ni = 0; ni < 2; ++ni)
#pragma unroll
                for (int i = 0; i < 4; ++i)
                    C[(size_t)(m0 + wr + mi * 16 + g * 4 + i) * ldc
                      + n0 + wc + ni * 16 + n] = f2bf(acc[mi * 2 + ni][i]);
    }
};
struct EpiStoreF32 {             // BN=128
    float* C; int ldc;
    __device__ void operator()(const f32x4* acc, int m0, int n0, int wr, int wc,
                               int g, int n) const {
#pragma unroll
        for (int mi = 0; mi < 4; ++mi)
#pragma unroll
            for (int ni = 0; ni < 4; ++ni)
#pragma unroll
                for (int i = 0; i < 4; ++i)
                    C[(size_t)(m0 + wr + mi * 16 + g * 4 + i) * ldc
                      + n0 + wc + ni * 16 + n] = acc[mi * 4 + ni][i];
    }
};
// q GEMM: write Qb[bh][l][192] with fused YaRN RoPE (BN=128, N=3072)
struct EpiQ {
    u16* Qb; const float* tab;
    __device__ void operator()(const f32x4* acc, int m0, int n0, int wr, int wc,
                               int g, int n) const {
        int c0 = n0 + wc;                 // multiple of 64
        int h = c0 / 192, r0 = c0 % 192;  // r0 in {0,64,128}
#pragma unroll
        for (int mi = 0; mi < 4; ++mi)
#pragma unroll
            for (int i = 0; i < 4; ++i) {
                int rr = m0 + wr + mi * 16 + g * 4 + i;
                int b = rr >> 11, l = rr & 2047;
                size_t base = ((size_t)(b * 16 + h) * 2048 + l) * 192;
                if (r0 < 128) {
#pragma unroll
                    for (int ni = 0; ni < 4; ++ni)
                        Qb[base + r0 + ni * 16 + n] = f2bf(acc[mi * 4 + ni][i]);
                } else {
#pragma unroll
                    for (int ni = 0; ni < 2; ++ni) {
                        int j = ni * 16 + n;
                        float cs = tab[l * 64 + j], sn = tab[l * 64 + 32 + j];
                        float lo = acc[mi * 4 + ni][i];
                        float hi = acc[mi * 4 + ni + 2][i];
                        Qb[base + 128 + j] = f2bf(lo * cs - hi * sn);
                        Qb[base + 160 + j] = f2bf(hi * cs + lo * sn);
                    }
                }
            }
    }
};
// kvb GEMM: k_nope -> Kb (XOR-swizzled rows), v -> Vc[bl][h*128+dv]
struct EpiKV {
    u16* Kb; u16* Vc;
    __device__ void operator()(const f32x4* acc, int m0, int n0, int wr, int wc,
                               int g, int n) const {
        int c0 = n0 + wc;                 // multiple of 64
        int h = c0 >> 8, r0 = c0 & 255;   // r0 in {0,64,128,192}
#pragma unroll
        for (int mi = 0; mi < 4; ++mi)
#pragma unroll
            for (int i = 0; i < 4; ++i) {
                int rr = m0 + wr + mi * 16 + g * 4 + i;
                int b = rr >> 11, l = rr & 2047;
                if (r0 < 128) {
                    size_t base = ((size_t)(b * 16 + h) * 2048 + l) * 192;
#pragma unroll
                    for (int ni = 0; ni < 4; ++ni) {
                        int d = r0 + ni * 16 + n;
                        Kb[base + kswz(l, d)] = f2bf(acc[mi * 4 + ni][i]);
                    }
                } else {
#pragma unroll
                    for (int ni = 0; ni < 4; ++ni)
                        Vc[(size_t)rr * 2048 + h * 128 + (r0 - 128) + ni * 16 + n]
                            = f2bf(acc[mi * 4 + ni][i]);
                }
            }
    }
};

// --------------------------------------------------------------- bf16 GEMM
template<int BN, class Epi>
__global__ __launch_bounds__(256) void gemm_bf16(
    const u16* __restrict__ A, int lda,
    const u16* __restrict__ Bt, int ldb,
    int K, Epi epi)
{
    constexpr int NI = BN / 32;
    __shared__ u16 As[128 * 32];
    __shared__ u16 Bs[BN * 32];
    const int tid = threadIdx.x;
    const int w = tid >> 6, lane = tid & 63;
    const int g = lane >> 4, n = lane & 15;
    const int wr = (w >> 1) * 64, wc = (w & 1) * (BN / 2);
    const int m0 = blockIdx.y * 128, n0 = blockIdx.x * BN;
    const int arow = lane >> 2, acol = (lane & 3) * 8;

    f32x4 acc[4][NI];
#pragma unroll
    for (int mi = 0; mi < 4; ++mi)
#pragma unroll
        for (int ni = 0; ni < NI; ++ni) acc[mi][ni] = (f32x4){0.f, 0.f, 0.f, 0.f};

    for (int k0 = 0; k0 < K; k0 += 32) {
        __syncthreads();
#pragma unroll
        for (int i = 0; i < 2; ++i) {     // A tile: 128x32
            int seg = w * 2 + i;
            int row = seg * 16 + arow;
            g2l16(A + (size_t)(m0 + row) * lda + k0 + acol, &As[seg * 512]);
        }
        if constexpr (BN == 128) {
#pragma unroll
            for (int i = 0; i < 2; ++i) {
                int seg = w * 2 + i;
                int row = seg * 16 + arow;
                g2l16(Bt + (size_t)(n0 + row) * ldb + k0 + acol, &Bs[seg * 512]);
            }
        } else {
            int row = w * 16 + arow;
            g2l16(Bt + (size_t)(n0 + row) * ldb + k0 + acol, &Bs[w * 512]);
        }
        __syncthreads();

        bf16x8 af[4], bf[NI];
#pragma unroll
        for (int mi = 0; mi < 4; ++mi)
            af[mi] = *(const bf16x8*)&As[(wr + mi * 16 + n) * 32 + g * 8];
#pragma unroll
        for (int ni = 0; ni < NI; ++ni)
            bf[ni] = *(const bf16x8*)&Bs[(wc + ni * 16 + n) * 32 + g * 8];
#pragma unroll
        for (int mi = 0; mi < 4; ++mi)
#pragma unroll
            for (int ni = 0; ni < NI; ++ni)
                acc[mi][ni] = __builtin_amdgcn_mfma_f32_16x16x32_bf16(
                    af[mi], bf[ni], acc[mi][ni], 0, 0, 0);
    }
    epi(&acc[0][0], m0, n0, wr, wc, g, n);
}

// ------------------------------------------------ k_rope fill of Kb (swizzled)
__global__ __launch_bounds__(256) void krope(
    const u16* __restrict__ kvf_b, u16* __restrict__ Kb,
    const float* __restrict__ tab)
{
    int idx = blockIdx.x * 256 + threadIdx.x;   // 32 bh * 2048 l * 32 j
    int j = idx & 31;
    int l = (idx >> 5) & 2047;
    int bh = idx >> 16;
    int b = bh >> 4;
    size_t row = (size_t)(b * 2048 + l);
    float x0 = bf2f(kvf_b[row * 576 + 512 + j]);
    float x1 = bf2f(kvf_b[row * 576 + 544 + j]);
    float cs = tab[l * 64 + j], sn = tab[l * 64 + 32 + j];
    size_t base = ((size_t)bh * 2048 + l) * 192;
    Kb[base + kswz(l, 128 + j)] = f2bf(x0 * cs - x1 * sn);
    Kb[base + kswz(l, 160 + j)] = f2bf(x1 * cs + x0 * sn);
}

// ----------------------------------- Vc[bl][h*128+dv] -> Vt[bh][128][2048] bf16
__global__ __launch_bounds__(256) void vtrans_b(
    const u16* __restrict__ Vc, u16* __restrict__ Vt)
{
    __shared__ u16 t[64][72];
    const int tid = threadIdx.x;
    const int bh = blockIdx.z, b = bh >> 4, h = bh & 15;
    const int l0 = blockIdx.x * 64, dv0 = blockIdx.y * 64;
    {
        int lr = tid >> 2, dc = (tid & 3) * 16;
        const u16* src = Vc + (size_t)(b * 2048 + l0 + lr) * 2048 + h * 128 + dv0 + dc;
        uint4 v0 = *(const uint4*)src;
        uint4 v1 = *(const uint4*)(src + 8);
        *(uint4*)&t[lr][dc] = v0;
        *(uint4*)&t[lr][dc + 8] = v1;
    }
    __syncthreads();
    {
        int dvr = tid >> 2, lc = (tid & 3) * 16;
        union { uint4 v[2]; u16 s[16]; } u;
#pragma unroll
        for (int j = 0; j < 16; ++j) u.s[j] = t[lc + j][dvr];
        uint4* dst = (uint4*)(Vt + ((size_t)bh * 128 + dv0 + dvr) * 2048 + l0 + lc);
        dst[0] = u.v[0]; dst[1] = u.v[1];
    }
}

// -------------------------------------------------------- MFMA flash attention
// grid (16, 32): block x handles q-tiles {x, 31-x} (64 rows each) of head bh.
// 4 waves; wave w owns 16 q rows. KVBLK=64. K from swizzled Kb via
// global_load_lds; V from Vt via global_load_lds with pre-swizzled source.
__global__ __launch_bounds__(256) void attn_mfma(
    const u16* __restrict__ Qb,   // [32][2048][192]
    const u16* __restrict__ Kb,   // [32][2048][192]  (rows XOR-swizzled)
    const u16* __restrict__ Vt,   // [32][128][2048]
    u16* __restrict__ outp)       // [4096][2048] bf16
{
    __shared__ u16 Kl[64 * 192];      // swizzled rows, 24 KB
    __shared__ u16 Vl[128 * 64];      // swizzled rows, 16 KB
    __shared__ u16 Pt[4][64][20];     // per-wave P^T, stride 20 (2-way banks)

    const int tid = threadIdx.x;
    const int w = tid >> 6, lane = tid & 63;
    const int g = lane >> 4, n = lane & 15;
    const int n7 = n & 7;
    const int bh = blockIdx.y, b = bh >> 4;
    const float scale = 0.07216878364870323f;   // 1/sqrt(192)

    for (int half = 0; half < 2; ++half) {
        const int qt = half ? (31 - blockIdx.x) : blockIdx.x;
        const int qb0 = qt << 6;

        // Q fragments (A-operand: row = n, k = g*8+j per 32-chunk)
        bf16x8 qf[6];
        {
            const int qrow = qb0 + w * 16 + n;
            const u16* qp = Qb + ((size_t)bh * L_ + qrow) * 192 + g * 8;
#pragma unroll
            for (int kk = 0; kk < 6; ++kk)
                qf[kk] = *(const bf16x8*)(qp + kk * 32);
        }

        f32x4 acc[8];
#pragma unroll
        for (int dt = 0; dt < 8; ++dt) acc[dt] = (f32x4){0.f, 0.f, 0.f, 0.f};
        float mi[4] = {-INFINITY, -INFINITY, -INFINITY, -INFINITY};
        float li[4] = {0.f, 0.f, 0.f, 0.f};

        const int ntiles = qt + 1;
        for (int kt = 0; kt < ntiles; ++kt) {
            const int kb = kt << 6;
            __syncthreads();
            {   // K tile: contiguous 24 KB (rows already swizzled in Kb)
                const u16* Ksrc = Kb + ((size_t)bh * L_ + kb) * 192;
#pragma unroll
                for (int i = 0; i < 6; ++i) {
                    int c = i * 4 + w;
                    g2l16(Ksrc + c * 512 + lane * 8, &Kl[c * 512]);
                }
            }
            {   // V tile: 16 KB; lane fetches global block (lane&7)^(dv&7)
                const u16* Vsrc = Vt + (size_t)bh * 128 * 2048 + kb;
#pragma unroll
                for (int i = 0; i < 4; ++i) {
                    int c = i * 4 + w;
                    int dv = c * 8 + (lane >> 3);
                    int blk = (lane & 7) ^ (lane >> 3);
                    g2l16(Vsrc + (size_t)dv * 2048 + blk * 8, &Vl[c * 512]);
                }
            }
            __syncthreads();

            // ---- QK^T: 4 col-tiles of 16 keys
            f32x4 s[4];
#pragma unroll
            for (int c = 0; c < 4; ++c) s[c] = (f32x4){0.f, 0.f, 0.f, 0.f};
#pragma unroll
            for (int c = 0; c < 4; ++c)
#pragma unroll
                for (int kk = 0; kk < 6; ++kk) {
                    bf16x8 kf = *(const bf16x8*)
                        &Kl[(c * 16 + n) * 192 + ((kk * 4 + g) ^ n7) * 8];
                    s[c] = __builtin_amdgcn_mfma_f32_16x16x32_bf16(qf[kk], kf, s[c], 0, 0, 0);
                }

            // ---- mask + online softmax (rows g*4+i, cols c*16+n)
            float al[4];
#pragma unroll
            for (int i = 0; i < 4; ++i) {
                int qr = qb0 + w * 16 + g * 4 + i;
                float v[4];
#pragma unroll
                for (int c = 0; c < 4; ++c)
                    v[c] = (kb + c * 16 + n <= qr) ? s[c][i] * scale : -1e30f;
                float mx = fmaxf(fmaxf(v[0], v[1]), fmaxf(v[2], v[3]));
                mx = fmaxf(mx, __shfl_xor(mx, 1));
                mx = fmaxf(mx, __shfl_xor(mx, 2));
                mx = fmaxf(mx, __shfl_xor(mx, 4));
                mx = fmaxf(mx, __shfl_xor(mx, 8));
                float mnew = fmaxf(mi[i], mx);
                float p0 = expf(v[0] - mnew);
                float p1 = expf(v[1] - mnew);
                float p2 = expf(v[2] - mnew);
                float p3 = expf(v[3] - mnew);
                float ts = (p0 + p1) + (p2 + p3);
                ts += __shfl_xor(ts, 1);
                ts += __shfl_xor(ts, 2);
                ts += __shfl_xor(ts, 4);
                ts += __shfl_xor(ts, 8);
                float a = expf(mi[i] - mnew);
                li[i] = li[i] * a + ts;
                mi[i] = mnew;
                al[i] = a;
                s[0][i] = p0; s[1][i] = p1; s[2][i] = p2; s[3][i] = p3;
            }
#pragma unroll
            for (int c = 0; c < 4; ++c) {   // P^T pack: Pt[k=c*16+n][row g*4..+3]
                union { double d; u16 hh[4]; } u;
#pragma unroll
                for (int i = 0; i < 4; ++i) u.hh[i] = f2bf(s[c][i]);
                *(double*)&Pt[w][c * 16 + n][g * 4] = u.d;
            }
            asm volatile("s_waitcnt lgkmcnt(0)" ::: "memory");
            __builtin_amdgcn_sched_barrier(0);

            // ---- P A-fragments: P[row=n][k] = Pt[k][n], k = ks*32+g*8+j
            union { bf16x8 v; short e[8]; } pf[2];
#pragma unroll
            for (int ks = 0; ks < 2; ++ks)
#pragma unroll
                for (int j = 0; j < 8; ++j)
                    pf[ks].e[j] = *(const short*)&Pt[w][ks * 32 + g * 8 + j][n];

            // ---- PV: 8 dv col-tiles x 2 k-chunks
#pragma unroll
            for (int dt = 0; dt < 8; ++dt) {
#pragma unroll
                for (int i = 0; i < 4; ++i) acc[dt][i] *= al[i];
#pragma unroll
                for (int ks = 0; ks < 2; ++ks) {
                    bf16x8 vf = *(const bf16x8*)
                        &Vl[(dt * 16 + n) * 64 + (((ks * 4 + g) ^ n7) << 3)];
                    acc[dt] = __builtin_amdgcn_mfma_f32_16x16x32_bf16(pf[ks].v, vf, acc[dt], 0, 0, 0);
                }
            }
        }

        // epilogue for this q-tile
#pragma unroll
        for (int dt = 0; dt < 8; ++dt) {
#pragma unroll
            for (int i = 0; i < 4; ++i) {
                int qr = qb0 + w * 16 + g * 4 + i;
                outp[(size_t)(b * L_ + qr) * 2048 + (bh & 15) * 128 + dt * 16 + n]
                    = f2bf(acc[dt][i] / li[i]);
            }
        }
    }
}

// ------------------------------------------------------------------- launcher
extern "C" void kernel_launch(void* const* d_in, const int* in_sizes, int n_in,
                              void* d_out, int out_size, void* d_ws, size_t ws_size,
                              hipStream_t stream)
{
    const float* x     = (const float*)d_in[0];
    const float* w_qa  = (const float*)d_in[1];
    const float* qnw   = (const float*)d_in[2];
    const float* w_qb  = (const float*)d_in[3];
    const float* w_kva = (const float*)d_in[4];
    const float* kvnw  = (const float*)d_in[5];
    const float* w_kvb = (const float*)d_in[6];
    const float* w_o   = (const float*)d_in[7];
    float* out = (float*)d_out;
    u16* W = (u16*)d_ws;

    // ---- workspace layout (u16 elems), total 131.9 MB
    const size_t o_wt_qa  = 0;
    const size_t o_wt_qb  = o_wt_qa  + (size_t)2048 * 1536;
    const size_t o_wt_kva = o_wt_qb  + (size_t)1536 * 3072;
    const size_t o_wt_kvb = o_wt_kva + (size_t)2048 * 576;
    const size_t o_wt_o   = o_wt_kvb + (size_t)512 * 4096;
    const size_t o_tab    = o_wt_o   + (size_t)2048 * 2048;   // float[2048*64]
    const size_t o_Qb     = o_tab    + 262144;
    const size_t o_Kb     = o_Qb     + 12582912;
    const size_t o_Vt     = o_Kb     + 12582912;
    const size_t o_Vc     = o_Vt     + 8388608;
    const size_t o_xb     = o_Vc     + 8388608;

    u16* Wt_qa  = W + o_wt_qa;
    u16* Wt_qb  = W + o_wt_qb;
    u16* Wt_kva = W + o_wt_kva;
    u16* Wt_kvb = W + o_wt_kvb;
    u16* Wt_o   = W + o_wt_o;
    float* tab  = (float*)(W + o_tab);
    u16* Qb     = W + o_Qb;
    u16* qaR_b  = W + o_Kb;
    u16* qa_b   = W + o_Kb + 6291456;
    u16* Kb     = W + o_Kb;
    u16* kvf_b  = W + o_Vt;
    u16* kvc_b  = W + o_Vt + 2359296;
    u16* Vt     = W + o_Vt;
    u16* Vc     = W + o_Vc;
    u16* atto_b = W + o_Vc;
    u16* x_b    = W + o_xb;

    dim3 blk(256);

    yarn_tab<<<(2048 * 32) / 256, blk, 0, stream>>>(tab);
    cvt_bf16<<<4096, blk, 0, stream>>>(x, x_b);
    wtrans<<<dim3(1536 / 64, 2048 / 64), blk, 0, stream>>>(w_qa,  Wt_qa,  2048, 1536);
    wtrans<<<dim3(3072 / 64, 1536 / 64), blk, 0, stream>>>(w_qb,  Wt_qb,  1536, 3072);
    wtrans<<<dim3( 576 / 64, 2048 / 64), blk, 0, stream>>>(w_kva, Wt_kva, 2048, 576);
    wtrans<<<dim3(4096 / 64,  512 / 64), blk, 0, stream>>>(w_kvb, Wt_kvb, 512, 4096);
    wtrans<<<dim3(2048 / 64, 2048 / 64), blk, 0, stream>>>(w_o,   Wt_o,   2048, 2048);

    // q chain
    gemm_bf16<128, EpiStoreBf16_4><<<dim3(12, 32), blk, 0, stream>>>(
        x_b, 2048, Wt_qa, 2048, 2048, EpiStoreBf16_4{qaR_b, 1536});
    rmsnorm_b<<<4096, blk, 0, stream>>>(qaR_b, 1536, qa_b, 1536, qnw, 1536);
    gemm_bf16<128, EpiQ><<<dim3(24, 32), blk, 0, stream>>>(
        qa_b, 1536, Wt_qb, 1536, 1536, EpiQ{Qb, tab});

    // kv chain
    gemm_bf16<64, EpiStoreBf16_2><<<dim3(9, 32), blk, 0, stream>>>(
        x_b, 2048, Wt_kva, 2048, 2048, EpiStoreBf16_2{kvf_b, 576});
    rmsnorm_b<<<4096, blk, 0, stream>>>(kvf_b, 576, kvc_b, 512, kvnw, 512);
    gemm_bf16<128, EpiKV><<<dim3(32, 32), blk, 0, stream>>>(
        kvc_b, 512, Wt_kvb, 512, 512, EpiKV{Kb, Vc});
    krope<<<(32 * 2048 * 32) / 256, blk, 0, stream>>>(kvf_b, Kb, tab);
    vtrans_b<<<dim3(32, 2, 32), blk, 0, stream>>>(Vc, Vt);

    // attention + output projection
    attn_mfma<<<dim3(16, 32), blk, 0, stream>>>(Qb, Kb, Vt, atto_b);
    gemm_bf16<128, EpiStoreF32><<<dim3(16, 32), blk, 0, stream>>>(
        atto_b, 2048, Wt_o, 2048, 2048, EpiStoreF32{out, 2048});
}

// Round 6
// 403.762 us; speedup vs baseline: 12.3823x; 1.0787x over previous
//
#include <hip/hip_runtime.h>
#include <hip/hip_bf16.h>
#include <math.h>

#define H_    16
#define B_    2
#define L_    2048
#define HID_  2048
#define QL_   1536
#define KVL_  512

typedef unsigned short u16;
typedef __attribute__((ext_vector_type(8))) short bf16x8;
typedef __attribute__((ext_vector_type(4))) float f32x4;

__device__ __forceinline__ float bf2f(u16 u) {
    unsigned int x = ((unsigned int)u) << 16;
    return __uint_as_float(x);
}
__device__ __forceinline__ u16 f2bf(float f) {
    __hip_bfloat16 b = __float2bfloat16(f);
    return *(u16*)&b;
}
__device__ __forceinline__ void g2l16(const void* g, void* l) {
    __builtin_amdgcn_global_load_lds(
        (const __attribute__((address_space(1))) unsigned int*)g,
        (__attribute__((address_space(3))) unsigned int*)l,
        16, 0, 0);
}
// Kb row swizzle: element (l, d) of a K row is stored at column kswz(l, d)
__device__ __forceinline__ int kswz(int l, int d) {
    return (((d >> 3) ^ (l & 7)) << 3) | (d & 7);
}

// ----------------------------------------------------------------- YaRN table
__device__ inline void yarn_cs(int l, int j, float& c, float& s)
{
    float invf = expf(-(float)(2 * j) * (9.210340371976184f / 64.f));
    float wavelen = 6.283185307179586f / invf;
    float ramp = (8192.f / wavelen - 1.f) * (1.f / 3.f);
    ramp = fminf(fmaxf(ramp, 0.f), 1.f);
    float invf2 = invf * (1.f - ramp) + invf * (1.f / 16.f) * ramp;
    float ang = (float)l * invf2;
    const float af = 1.2772588722239781f;
    c = cosf(ang) * af;
    s = sinf(ang) * af;
}

__global__ __launch_bounds__(256) void yarn_tab(float* __restrict__ tab)
{
    int idx = blockIdx.x * 256 + threadIdx.x;   // 2048*32
    int l = idx >> 5, j = idx & 31;
    float c, s; yarn_cs(l, j, c, s);
    tab[l * 64 + j] = c;
    tab[l * 64 + 32 + j] = s;
}

// ------------------------------------------------------------ fp32 -> bf16 cvt
__global__ __launch_bounds__(256) void cvt_bf16(
    const float* __restrict__ in, u16* __restrict__ outp)
{
    int idx = blockIdx.x * 256 + threadIdx.x;
    float4 a = ((const float4*)in)[idx * 2];
    float4 b = ((const float4*)in)[idx * 2 + 1];
    union { uint4 v; u16 s[8]; } u;
    u.s[0] = f2bf(a.x); u.s[1] = f2bf(a.y); u.s[2] = f2bf(a.z); u.s[3] = f2bf(a.w);
    u.s[4] = f2bf(b.x); u.s[5] = f2bf(b.y); u.s[6] = f2bf(b.z); u.s[7] = f2bf(b.w);
    ((uint4*)outp)[idx] = u.v;
}

// ------------------------------------- weight transpose W[K][N] -> Wt[N][K] bf16
__global__ __launch_bounds__(256) void wtrans(
    const float* __restrict__ W, u16* __restrict__ Wt, int K, int N)
{
    __shared__ float t[64][65];
    const int n0 = blockIdx.x * 64, k0 = blockIdx.y * 64;
    const int tid = threadIdx.x;
    {
        int lr = tid >> 2, nc = (tid & 3) * 16;
        const float* src = W + (size_t)(k0 + lr) * N + n0 + nc;
#pragma unroll
        for (int j = 0; j < 16; j += 4) {
            float4 v = *(const float4*)(src + j);
            t[lr][nc + j] = v.x; t[lr][nc + j + 1] = v.y;
            t[lr][nc + j + 2] = v.z; t[lr][nc + j + 3] = v.w;
        }
    }
    __syncthreads();
    {
        int nr = tid >> 2, kc = (tid & 3) * 16;
        union { uint4 v[2]; u16 s[16]; } u;
#pragma unroll
        for (int j = 0; j < 16; ++j) u.s[j] = f2bf(t[kc + j][nr]);
        uint4* dst = (uint4*)(Wt + (size_t)(n0 + nr) * K + k0 + kc);
        dst[0] = u.v[0]; dst[1] = u.v[1];
    }
}

// ------------------------------------------------------- RMSNorm bf16 -> bf16
__global__ __launch_bounds__(256) void rmsnorm_b(
    const u16* __restrict__ in, int istride,
    u16* __restrict__ outp, int ostride,
    const float* __restrict__ w, int ncols)
{
    const int row = blockIdx.x, tid = threadIdx.x;
    const u16* ir = in + (size_t)row * istride;
    const int nch = ncols >> 3;
    float ss = 0.f;
    for (int c = tid; c < nch; c += 256) {
        union { uint4 v; u16 s[8]; } u;
        u.v = *(const uint4*)(ir + c * 8);
#pragma unroll
        for (int j = 0; j < 8; ++j) { float v = bf2f(u.s[j]); ss += v * v; }
    }
#pragma unroll
    for (int o = 32; o > 0; o >>= 1) ss += __shfl_xor(ss, o);
    __shared__ float red[4];
    if ((tid & 63) == 0) red[tid >> 6] = ss;
    __syncthreads();
    float tot = red[0] + red[1] + red[2] + red[3];
    float sc = rsqrtf(tot / (float)ncols + 1e-6f);
    u16* orow = outp + (size_t)row * ostride;
    for (int c = tid; c < nch; c += 256) {
        union { uint4 v; u16 s[8]; } u, o2;
        u.v = *(const uint4*)(ir + c * 8);
#pragma unroll
        for (int j = 0; j < 8; ++j)
            o2.s[j] = f2bf(bf2f(u.s[j]) * sc * w[c * 8 + j]);
        *(uint4*)(orow + c * 8) = o2.v;
    }
}

// ------------------------------------------------------------- GEMM epilogues
struct EpiStoreBf16_4 {          // BN=128
    u16* C; int ldc;
    __device__ void operator()(const f32x4* acc, int m0, int n0, int wr, int wc,
                               int g, int n) const {
#pragma unroll
        for (int mi = 0; mi < 4; ++mi)
#pragma unroll
            for (int ni = 0; ni < 4; ++ni)
#pragma unroll
                for (int i = 0; i < 4; ++i)
                    C[(size_t)(m0 + wr + mi * 16 + g * 4 + i) * ldc
                      + n0 + wc + ni * 16 + n] = f2bf(acc[mi * 4 + ni][i]);
    }
};
struct EpiStoreBf16_2 {          // BN=64
    u16* C; int ldc;
    __device__ void operator()(const f32x4* acc, int m0, int n0, int wr, int wc,
                               int g, int n) const {
#pragma unroll
        for (int mi = 0; mi < 4; ++mi)
#pragma unroll
            for (int ni = 0; ni < 2; ++ni)
#pragma unroll
                for (int i = 0; i < 4; ++i)
                    C[(size_t)(m0 + wr + mi * 16 + g * 4 + i) * ldc
                      + n0 + wc + ni * 16 + n] = f2bf(acc[mi * 2 + ni][i]);
    }
};
struct EpiStoreF32 {             // BN=128
    float* C; int ldc;
    __device__ void operator()(const f32x4* acc, int m0, int n0, int wr, int wc,
                               int g, int n) const {
#pragma unroll
        for (int mi = 0; mi < 4; ++mi)
#pragma unroll
            for (int ni = 0; ni < 4; ++ni)
#pragma unroll
                for (int i = 0; i < 4; ++i)
                    C[(size_t)(m0 + wr + mi * 16 + g * 4 + i) * ldc
                      + n0 + wc + ni * 16 + n] = acc[mi * 4 + ni][i];
    }
};
// q GEMM: write Qb[bh][l][192] with fused YaRN RoPE (BN=128, N=3072)
struct EpiQ {
    u16* Qb; const float* tab;
    __device__ void operator()(const f32x4* acc, int m0, int n0, int wr, int wc,
                               int g, int n) const {
        int c0 = n0 + wc;                 // multiple of 64
        int h = c0 / 192, r0 = c0 % 192;  // r0 in {0,64,128}
#pragma unroll
        for (int mi = 0; mi < 4; ++mi)
#pragma unroll
            for (int i = 0; i < 4; ++i) {
                int rr = m0 + wr + mi * 16 + g * 4 + i;
                int b = rr >> 11, l = rr & 2047;
                size_t base = ((size_t)(b * 16 + h) * 2048 + l) * 192;
                if (r0 < 128) {
#pragma unroll
                    for (int ni = 0; ni < 4; ++ni)
                        Qb[base + r0 + ni * 16 + n] = f2bf(acc[mi * 4 + ni][i]);
                } else {
#pragma unroll
                    for (int ni = 0; ni < 2; ++ni) {
                        int j = ni * 16 + n;
                        float cs = tab[l * 64 + j], sn = tab[l * 64 + 32 + j];
                        float lo = acc[mi * 4 + ni][i];
                        float hi = acc[mi * 4 + ni + 2][i];
                        Qb[base + 128 + j] = f2bf(lo * cs - hi * sn);
                        Qb[base + 160 + j] = f2bf(hi * cs + lo * sn);
                    }
                }
            }
    }
};
// kvb GEMM: k_nope -> Kb (XOR-swizzled rows), v -> Vc[bl][h*128+dv]
struct EpiKV {
    u16* Kb; u16* Vc;
    __device__ void operator()(const f32x4* acc, int m0, int n0, int wr, int wc,
                               int g, int n) const {
        int c0 = n0 + wc;                 // multiple of 64
        int h = c0 >> 8, r0 = c0 & 255;   // r0 in {0,64,128,192}
#pragma unroll
        for (int mi = 0; mi < 4; ++mi)
#pragma unroll
            for (int i = 0; i < 4; ++i) {
                int rr = m0 + wr + mi * 16 + g * 4 + i;
                int b = rr >> 11, l = rr & 2047;
                if (r0 < 128) {
                    size_t base = ((size_t)(b * 16 + h) * 2048 + l) * 192;
#pragma unroll
                    for (int ni = 0; ni < 4; ++ni) {
                        int d = r0 + ni * 16 + n;
                        Kb[base + kswz(l, d)] = f2bf(acc[mi * 4 + ni][i]);
                    }
                } else {
#pragma unroll
                    for (int ni = 0; ni < 4; ++ni)
                        Vc[(size_t)rr * 2048 + h * 128 + (r0 - 128) + ni * 16 + n]
                            = f2bf(acc[mi * 4 + ni][i]);
                }
            }
    }
};

// --------------------------------------------------------------- bf16 GEMM
template<int BN, class Epi>
__global__ __launch_bounds__(256) void gemm_bf16(
    const u16* __restrict__ A, int lda,
    const u16* __restrict__ Bt, int ldb,
    int K, Epi epi)
{
    constexpr int NI = BN / 32;
    __shared__ u16 As[128 * 32];
    __shared__ u16 Bs[BN * 32];
    const int tid = threadIdx.x;
    const int w = tid >> 6, lane = tid & 63;
    const int g = lane >> 4, n = lane & 15;
    const int wr = (w >> 1) * 64, wc = (w & 1) * (BN / 2);
    const int m0 = blockIdx.y * 128, n0 = blockIdx.x * BN;
    const int arow = lane >> 2, acol = (lane & 3) * 8;

    f32x4 acc[4][NI];
#pragma unroll
    for (int mi = 0; mi < 4; ++mi)
#pragma unroll
        for (int ni = 0; ni < NI; ++ni) acc[mi][ni] = (f32x4){0.f, 0.f, 0.f, 0.f};

    for (int k0 = 0; k0 < K; k0 += 32) {
        __syncthreads();
#pragma unroll
        for (int i = 0; i < 2; ++i) {     // A tile: 128x32
            int seg = w * 2 + i;
            int row = seg * 16 + arow;
            g2l16(A + (size_t)(m0 + row) * lda + k0 + acol, &As[seg * 512]);
        }
        if constexpr (BN == 128) {
#pragma unroll
            for (int i = 0; i < 2; ++i) {
                int seg = w * 2 + i;
                int row = seg * 16 + arow;
                g2l16(Bt + (size_t)(n0 + row) * ldb + k0 + acol, &Bs[seg * 512]);
            }
        } else {
            int row = w * 16 + arow;
            g2l16(Bt + (size_t)(n0 + row) * ldb + k0 + acol, &Bs[w * 512]);
        }
        __syncthreads();

        bf16x8 af[4], bf[NI];
#pragma unroll
        for (int mi = 0; mi < 4; ++mi)
            af[mi] = *(const bf16x8*)&As[(wr + mi * 16 + n) * 32 + g * 8];
#pragma unroll
        for (int ni = 0; ni < NI; ++ni)
            bf[ni] = *(const bf16x8*)&Bs[(wc + ni * 16 + n) * 32 + g * 8];
#pragma unroll
        for (int mi = 0; mi < 4; ++mi)
#pragma unroll
            for (int ni = 0; ni < NI; ++ni)
                acc[mi][ni] = __builtin_amdgcn_mfma_f32_16x16x32_bf16(
                    af[mi], bf[ni], acc[mi][ni], 0, 0, 0);
    }
    epi(&acc[0][0], m0, n0, wr, wc, g, n);
}

// ------------------------------------------------ k_rope fill of Kb (swizzled)
__global__ __launch_bounds__(256) void krope(
    const u16* __restrict__ kvf_b, u16* __restrict__ Kb,
    const float* __restrict__ tab)
{
    int idx = blockIdx.x * 256 + threadIdx.x;   // 32 bh * 2048 l * 32 j
    int j = idx & 31;
    int l = (idx >> 5) & 2047;
    int bh = idx >> 16;
    int b = bh >> 4;
    size_t row = (size_t)(b * 2048 + l);
    float x0 = bf2f(kvf_b[row * 576 + 512 + j]);
    float x1 = bf2f(kvf_b[row * 576 + 544 + j]);
    float cs = tab[l * 64 + j], sn = tab[l * 64 + 32 + j];
    size_t base = ((size_t)bh * 2048 + l) * 192;
    Kb[base + kswz(l, 128 + j)] = f2bf(x0 * cs - x1 * sn);
    Kb[base + kswz(l, 160 + j)] = f2bf(x1 * cs + x0 * sn);
}

// ----------------------------------- Vc[bl][h*128+dv] -> Vt[bh][128][2048] bf16
__global__ __launch_bounds__(256) void vtrans_b(
    const u16* __restrict__ Vc, u16* __restrict__ Vt)
{
    __shared__ u16 t[64][72];
    const int tid = threadIdx.x;
    const int bh = blockIdx.z, b = bh >> 4, h = bh & 15;
    const int l0 = blockIdx.x * 64, dv0 = blockIdx.y * 64;
    {
        int lr = tid >> 2, dc = (tid & 3) * 16;
        const u16* src = Vc + (size_t)(b * 2048 + l0 + lr) * 2048 + h * 128 + dv0 + dc;
        uint4 v0 = *(const uint4*)src;
        uint4 v1 = *(const uint4*)(src + 8);
        *(uint4*)&t[lr][dc] = v0;
        *(uint4*)&t[lr][dc + 8] = v1;
    }
    __syncthreads();
    {
        int dvr = tid >> 2, lc = (tid & 3) * 16;
        union { uint4 v[2]; u16 s[16]; } u;
#pragma unroll
        for (int j = 0; j < 16; ++j) u.s[j] = t[lc + j][dvr];
        uint4* dst = (uint4*)(Vt + ((size_t)bh * 128 + dv0 + dvr) * 2048 + l0 + lc);
        dst[0] = u.v[0]; dst[1] = u.v[1];
    }
}

// -------------------------------------------------------- MFMA flash attention
// grid (512): linear id XCD-swizzled so the 16 blocks sharing one (b,h)'s
// K/V run on the same XCD (L2 reuse). Block handles q-tiles {qtx, 31-qtx}.
__global__ __launch_bounds__(256) void attn_mfma(
    const u16* __restrict__ Qb,   // [32][2048][192]
    const u16* __restrict__ Kb,   // [32][2048][192]  (rows XOR-swizzled)
    const u16* __restrict__ Vt,   // [32][128][2048]
    u16* __restrict__ outp)       // [4096][2048] bf16
{
    __shared__ u16 Kl[64 * 192];      // swizzled rows, 24 KB
    __shared__ u16 Vl[128 * 64];      // swizzled rows, 16 KB
    __shared__ u16 Pt[4][64][20];     // per-wave P^T, stride 20 (2-way banks)

    const int tid = threadIdx.x;
    const int w = tid >> 6, lane = tid & 63;
    const int g = lane >> 4, n = lane & 15;
    const int n7 = n & 7;
    // XCD-aware swizzle: XCD = lin%8 gets swz in [xcd*64, xcd*64+64)
    // = 4 whole heads (16 blocks each) -> K/V panel resident in that XCD's L2.
    const int lin = blockIdx.x;
    const int swz = (lin & 7) * 64 + (lin >> 3);
    const int bh = swz >> 4, qtx = swz & 15;
    const int b = bh >> 4;
    const float scale = 0.07216878364870323f;   // 1/sqrt(192)

    for (int half = 0; half < 2; ++half) {
        const int qt = half ? (31 - qtx) : qtx;
        const int qb0 = qt << 6;

        // Q fragments (A-operand: row = n, k = g*8+j per 32-chunk)
        bf16x8 qf[6];
        {
            const int qrow = qb0 + w * 16 + n;
            const u16* qp = Qb + ((size_t)bh * L_ + qrow) * 192 + g * 8;
#pragma unroll
            for (int kk = 0; kk < 6; ++kk)
                qf[kk] = *(const bf16x8*)(qp + kk * 32);
        }

        f32x4 acc[8];
#pragma unroll
        for (int dt = 0; dt < 8; ++dt) acc[dt] = (f32x4){0.f, 0.f, 0.f, 0.f};
        float mi[4] = {-INFINITY, -INFINITY, -INFINITY, -INFINITY};
        float li[4] = {0.f, 0.f, 0.f, 0.f};

        const int ntiles = qt + 1;
        for (int kt = 0; kt < ntiles; ++kt) {
            const int kb = kt << 6;
            __syncthreads();
            {   // K tile: contiguous 24 KB (rows already swizzled in Kb)
                const u16* Ksrc = Kb + ((size_t)bh * L_ + kb) * 192;
#pragma unroll
                for (int i = 0; i < 6; ++i) {
                    int c = i * 4 + w;
                    g2l16(Ksrc + c * 512 + lane * 8, &Kl[c * 512]);
                }
            }
            {   // V tile: 16 KB; lane fetches global block (lane&7)^(dv&7)
                const u16* Vsrc = Vt + (size_t)bh * 128 * 2048 + kb;
#pragma unroll
                for (int i = 0; i < 4; ++i) {
                    int c = i * 4 + w;
                    int dv = c * 8 + (lane >> 3);
                    int blk = (lane & 7) ^ (lane >> 3);
                    g2l16(Vsrc + (size_t)dv * 2048 + blk * 8, &Vl[c * 512]);
                }
            }
            __syncthreads();

            // ---- QK^T: 4 col-tiles of 16 keys
            f32x4 s[4];
#pragma unroll
            for (int c = 0; c < 4; ++c) s[c] = (f32x4){0.f, 0.f, 0.f, 0.f};
#pragma unroll
            for (int c = 0; c < 4; ++c)
#pragma unroll
                for (int kk = 0; kk < 6; ++kk) {
                    bf16x8 kf = *(const bf16x8*)
                        &Kl[(c * 16 + n) * 192 + ((kk * 4 + g) ^ n7) * 8];
                    s[c] = __builtin_amdgcn_mfma_f32_16x16x32_bf16(qf[kk], kf, s[c], 0, 0, 0);
                }

            // ---- mask + online softmax (rows g*4+i, cols c*16+n)
            float al[4];
#pragma unroll
            for (int i = 0; i < 4; ++i) {
                int qr = qb0 + w * 16 + g * 4 + i;
                float v[4];
#pragma unroll
                for (int c = 0; c < 4; ++c)
                    v[c] = (kb + c * 16 + n <= qr) ? s[c][i] * scale : -1e30f;
                float mx = fmaxf(fmaxf(v[0], v[1]), fmaxf(v[2], v[3]));
                mx = fmaxf(mx, __shfl_xor(mx, 1));
                mx = fmaxf(mx, __shfl_xor(mx, 2));
                mx = fmaxf(mx, __shfl_xor(mx, 4));
                mx = fmaxf(mx, __shfl_xor(mx, 8));
                float mnew = fmaxf(mi[i], mx);
                float p0 = __expf(v[0] - mnew);
                float p1 = __expf(v[1] - mnew);
                float p2 = __expf(v[2] - mnew);
                float p3 = __expf(v[3] - mnew);
                float ts = (p0 + p1) + (p2 + p3);
                ts += __shfl_xor(ts, 1);
                ts += __shfl_xor(ts, 2);
                ts += __shfl_xor(ts, 4);
                ts += __shfl_xor(ts, 8);
                float a = __expf(mi[i] - mnew);
                li[i] = li[i] * a + ts;
                mi[i] = mnew;
                al[i] = a;
                s[0][i] = p0; s[1][i] = p1; s[2][i] = p2; s[3][i] = p3;
            }
#pragma unroll
            for (int c = 0; c < 4; ++c) {   // P^T pack: Pt[k=c*16+n][row g*4..+3]
                union { double d; u16 hh[4]; } u;
#pragma unroll
                for (int i = 0; i < 4; ++i) u.hh[i] = f2bf(s[c][i]);
                *(double*)&Pt[w][c * 16 + n][g * 4] = u.d;
            }
            asm volatile("s_waitcnt lgkmcnt(0)" ::: "memory");
            __builtin_amdgcn_sched_barrier(0);

            // ---- P A-fragments: P[row=n][k] = Pt[k][n], k = ks*32+g*8+j
            union { bf16x8 v; short e[8]; } pf[2];
#pragma unroll
            for (int ks = 0; ks < 2; ++ks)
#pragma unroll
                for (int j = 0; j < 8; ++j)
                    pf[ks].e[j] = *(const short*)&Pt[w][ks * 32 + g * 8 + j][n];

            // ---- PV: 8 dv col-tiles x 2 k-chunks
#pragma unroll
            for (int dt = 0; dt < 8; ++dt) {
#pragma unroll
                for (int i = 0; i < 4; ++i) acc[dt][i] *= al[i];
#pragma unroll
                for (int ks = 0; ks < 2; ++ks) {
                    bf16x8 vf = *(const bf16x8*)
                        &Vl[(dt * 16 + n) * 64 + (((ks * 4 + g) ^ n7) << 3)];
                    acc[dt] = __builtin_amdgcn_mfma_f32_16x16x32_bf16(pf[ks].v, vf, acc[dt], 0, 0, 0);
                }
            }
        }

        // epilogue for this q-tile
        float inv[4];
#pragma unroll
        for (int i = 0; i < 4; ++i) inv[i] = __frcp_rn(li[i]);
#pragma unroll
        for (int dt = 0; dt < 8; ++dt) {
#pragma unroll
            for (int i = 0; i < 4; ++i) {
                int qr = qb0 + w * 16 + g * 4 + i;
                outp[(size_t)(b * L_ + qr) * 2048 + (bh & 15) * 128 + dt * 16 + n]
                    = f2bf(acc[dt][i] * inv[i]);
            }
        }
    }
}

// ------------------------------------------------------------------- launcher
extern "C" void kernel_launch(void* const* d_in, const int* in_sizes, int n_in,
                              void* d_out, int out_size, void* d_ws, size_t ws_size,
                              hipStream_t stream)
{
    const float* x     = (const float*)d_in[0];
    const float* w_qa  = (const float*)d_in[1];
    const float* qnw   = (const float*)d_in[2];
    const float* w_qb  = (const float*)d_in[3];
    const float* w_kva = (const float*)d_in[4];
    const float* kvnw  = (const float*)d_in[5];
    const float* w_kvb = (const float*)d_in[6];
    const float* w_o   = (const float*)d_in[7];
    float* out = (float*)d_out;
    u16* W = (u16*)d_ws;

    // ---- workspace layout (u16 elems), total 131.9 MB
    const size_t o_wt_qa  = 0;
    const size_t o_wt_qb  = o_wt_qa  + (size_t)2048 * 1536;
    const size_t o_wt_kva = o_wt_qb  + (size_t)1536 * 3072;
    const size_t o_wt_kvb = o_wt_kva + (size_t)2048 * 576;
    const size_t o_wt_o   = o_wt_kvb + (size_t)512 * 4096;
    const size_t o_tab    = o_wt_o   + (size_t)2048 * 2048;   // float[2048*64]
    const size_t o_Qb     = o_tab    + 262144;
    const size_t o_Kb     = o_Qb     + 12582912;
    const size_t o_Vt     = o_Kb     + 12582912;
    const size_t o_Vc     = o_Vt     + 8388608;
    const size_t o_xb     = o_Vc     + 8388608;

    u16* Wt_qa  = W + o_wt_qa;
    u16* Wt_qb  = W + o_wt_qb;
    u16* Wt_kva = W + o_wt_kva;
    u16* Wt_kvb = W + o_wt_kvb;
    u16* Wt_o   = W + o_wt_o;
    float* tab  = (float*)(W + o_tab);
    u16* Qb     = W + o_Qb;
    u16* qaR_b  = W + o_Kb;
    u16* qa_b   = W + o_Kb + 6291456;
    u16* Kb     = W + o_Kb;
    u16* kvf_b  = W + o_Vt;
    u16* kvc_b  = W + o_Vt + 2359296;
    u16* Vt     = W + o_Vt;
    u16* Vc     = W + o_Vc;
    u16* atto_b = W + o_Vc;
    u16* x_b    = W + o_xb;

    dim3 blk(256);

    yarn_tab<<<(2048 * 32) / 256, blk, 0, stream>>>(tab);
    cvt_bf16<<<4096, blk, 0, stream>>>(x, x_b);
    wtrans<<<dim3(1536 / 64, 2048 / 64), blk, 0, stream>>>(w_qa,  Wt_qa,  2048, 1536);
    wtrans<<<dim3(3072 / 64, 1536 / 64), blk, 0, stream>>>(w_qb,  Wt_qb,  1536, 3072);
    wtrans<<<dim3( 576 / 64, 2048 / 64), blk, 0, stream>>>(w_kva, Wt_kva, 2048, 576);
    wtrans<<<dim3(4096 / 64,  512 / 64), blk, 0, stream>>>(w_kvb, Wt_kvb, 512, 4096);
    wtrans<<<dim3(2048 / 64, 2048 / 64), blk, 0, stream>>>(w_o,   Wt_o,   2048, 2048);

    // q chain
    gemm_bf16<128, EpiStoreBf16_4><<<dim3(12, 32), blk, 0, stream>>>(
        x_b, 2048, Wt_qa, 2048, 2048, EpiStoreBf16_4{qaR_b, 1536});
    rmsnorm_b<<<4096, blk, 0, stream>>>(qaR_b, 1536, qa_b, 1536, qnw, 1536);
    gemm_bf16<128, EpiQ><<<dim3(24, 32), blk, 0, stream>>>(
        qa_b, 1536, Wt_qb, 1536, 1536, EpiQ{Qb, tab});

    // kv chain
    gemm_bf16<64, EpiStoreBf16_2><<<dim3(9, 32), blk, 0, stream>>>(
        x_b, 2048, Wt_kva, 2048, 2048, EpiStoreBf16_2{kvf_b, 576});
    rmsnorm_b<<<4096, blk, 0, stream>>>(kvf_b, 576, kvc_b, 512, kvnw, 512);
    gemm_bf16<128, EpiKV><<<dim3(32, 32), blk, 0, stream>>>(
        kvc_b, 512, Wt_kvb, 512, 512, EpiKV{Kb, Vc});
    krope<<<(32 * 2048 * 32) / 256, blk, 0, stream>>>(kvf_b, Kb, tab);
    vtrans_b<<<dim3(32, 2, 32), blk, 0, stream>>>(Vc, Vt);

    // attention + output projection
    attn_mfma<<<dim3(512), blk, 0, stream>>>(Qb, Kb, Vt, atto_b);
    gemm_bf16<128, EpiStoreF32><<<dim3(16, 32), blk, 0, stream>>>(
        atto_b, 2048, Wt_o, 2048, 2048, EpiStoreF32{out, 2048});
}